// Round 7
// baseline (930.040 us; speedup 1.0000x reference)
//
#include <hip/hip_runtime.h>

typedef _Float16 f16_t;
typedef f16_t f16x4 __attribute__((ext_vector_type(4)));
typedef f16_t f16x8 __attribute__((ext_vector_type(8)));
typedef float f32x4 __attribute__((ext_vector_type(4)));

// NOTE operand order: we call MFMA(weight_frag, act_frag) -> D = (X*W)^T,
// so output layout is: edge/node = lane&15, 4 consecutive out-cols = (lane>>4)*4+qi.
#define MFMA16(a, b, c) __builtin_amdgcn_mfma_f32_16x16x32_f16((a), (b), (c), 0, 0, 0)

// bf16 round (RNE) of an f32 — matches the reference harness's input rounding.
// bf16 values at these magnitudes are exactly representable in f16.
__device__ __forceinline__ float bfr(float x) { return (float)(__bf16)x; }

// ---------------------------------------------------------------------------
// Pack fp32 weight matrices into f16 MFMA fragment order, bf16-rounded.
// frag (kstep, ntile): lane l, elem j -> W[kstep*32 + (l>>4)*8 + j][ntile*16 + (l&15)]
// stored at dst[doff + ((kstep*NT + ntile)*64 + l)*8 + j]
// ---------------------------------------------------------------------------
__global__ void pack_weights_kernel(
    const float* __restrict__ ew0, const float* __restrict__ ew1,
    const float* __restrict__ ew2, const float* __restrict__ eL,
    const float* __restrict__ nw0, const float* __restrict__ nw1,
    const float* __restrict__ nw2, const float* __restrict__ nL,
    f16_t* __restrict__ dst)
{
    int tid = blockIdx.x * 256 + threadIdx.x;
    int fid = tid >> 6, lane = tid & 63;
    const float* src; int Ncols, foff, doff;
    if (fid < 192)      { src = ew0; Ncols = 256; foff = 0;   doff = 0;      }
    else if (fid < 320) { src = ew1; Ncols = 256; foff = 192; doff = 98304;  }
    else if (fid < 384) { src = ew2; Ncols = 128; foff = 320; doff = 163840; }
    else if (fid < 416) { src = eL;  Ncols = 128; foff = 384; doff = 196608; }
    else if (fid < 544) { src = nw0; Ncols = 256; foff = 416; doff = 212992; }
    else if (fid < 672) { src = nw1; Ncols = 256; foff = 544; doff = 278528; }
    else if (fid < 736) { src = nw2; Ncols = 128; foff = 672; doff = 344064; }
    else                { src = nL;  Ncols = 128; foff = 736; doff = 376832; }
    int f = fid - foff;
    int NT = Ncols >> 4;
    int kstep = f / NT, ntile = f - kstep * NT;
    int col = ntile * 16 + (lane & 15);
    int kbase = kstep * 32 + ((lane >> 4) << 3);
    f16x8 out;
    #pragma unroll
    for (int j = 0; j < 8; ++j)
        out[j] = (f16_t)bfr(src[(size_t)(kbase + j) * Ncols + col]);
    *reinterpret_cast<f16x8*>(dst + (size_t)doff + ((size_t)f * 64 + lane) * 8) = out;
}

// ---------------------------------------------------------------------------
// Edge kernel: 64 edges/block, 1024 threads (16 waves), 2 blocks/CU.
// Single LDS X buffer reused: LN'd concat (stride 392) -> h1 (stride 264)
// -> h2 (stride 264). Swapped-operand MFMA: epilogues write b64 (4 f16 cols
// of one row) -> no 8-way bank conflicts; out_e via float4; atomics on 4
// consecutive cols. Residual e read from global (L2-hot from phase 0).
// ---------------------------------------------------------------------------
__launch_bounds__(1024, 8)
__global__ void edge_kernel(
    const float* __restrict__ vfeat, const float* __restrict__ efeat,
    const int* __restrict__ eidx,
    const float* __restrict__ lng, const float* __restrict__ lnb,
    const f16_t* __restrict__ pw,
    const float* __restrict__ b0, const float* __restrict__ b1,
    const float* __restrict__ b2,
    float* __restrict__ out_e, float* __restrict__ aggr, float* __restrict__ cnts,
    int Ee)
{
    __shared__ f16_t X[64 * 392];      // 50176 B, reused across layers
    __shared__ int cidx[64];

    const int t    = threadIdx.x;
    const int lane = t & 63;
    const int wv   = t >> 6;           // 0..15
    const size_t ebase = (size_t)blockIdx.x * 64;

    // ---- phase 0: gather + bf16-round -> f16 LDS + LN stats
    const int el = t >> 4;             // 0..63
    const int pp = t & 15;
    const size_t eg0 = ebase + el;
    const int r0 = eidx[eg0];
    const int c0 = eidx[(size_t)Ee + eg0];

    float s = 0.f, sq = 0.f;
    {
        const float4* e4 = (const float4*)efeat;
        const float4* v4 = (const float4*)vfeat;
        #pragma unroll
        for (int i = 0; i < 6; ++i) {
            int q = i * 16 + pp;                // f4 index within 96 (=384 floats)
            float4 r;
            if (q < 32)      r = e4[eg0 * 32 + q];
            else if (q < 64) r = v4[(size_t)r0 * 32 + (q - 32)];
            else             r = v4[(size_t)c0 * 32 + (q - 64)];
            r.x = bfr(r.x); r.y = bfr(r.y); r.z = bfr(r.z); r.w = bfr(r.w);
            f16x4 h;
            h[0] = (f16_t)r.x; h[1] = (f16_t)r.y; h[2] = (f16_t)r.z; h[3] = (f16_t)r.w;
            *reinterpret_cast<f16x4*>(&X[el * 392 + q * 4]) = h;
            s  += r.x + r.y + r.z + r.w;
            sq += r.x*r.x + r.y*r.y + r.z*r.z + r.w*r.w;
        }
        if (pp == 0) {
            cidx[el] = c0;
            unsafeAtomicAdd(&cnts[c0], 1.0f);
        }
    }
    #pragma unroll
    for (int off = 1; off < 16; off <<= 1) {
        s  += __shfl_xor(s, off);
        sq += __shfl_xor(sq, off);
    }
    const float mean = s * (1.f / 384.f);
    const float rstd = 1.f / sqrtf(sq * (1.f / 384.f) - mean * mean + 1e-5f);

    // ---- phase 1: normalize in place (same thread, same addresses -> ordered)
    {
        const float4* g4p = (const float4*)lng;
        const float4* bpp = (const float4*)lnb;
        #pragma unroll
        for (int i = 0; i < 6; ++i) {
            int q = i * 16 + pp;
            f16x4 h = *reinterpret_cast<f16x4*>(&X[el * 392 + q * 4]);
            float4 g = g4p[q]; float4 bb = bpp[q];
            h[0] = (f16_t)(((float)h[0] - mean) * rstd * bfr(g.x) + bfr(bb.x));
            h[1] = (f16_t)(((float)h[1] - mean) * rstd * bfr(g.y) + bfr(bb.y));
            h[2] = (f16_t)(((float)h[2] - mean) * rstd * bfr(g.z) + bfr(bb.z));
            h[3] = (f16_t)(((float)h[3] - mean) * rstd * bfr(g.w) + bfr(bb.w));
            *reinterpret_cast<f16x4*>(&X[el * 392 + q * 4]) = h;
        }
    }
    __syncthreads();

    const int r16 = lane & 15;
    const int g4i = lane >> 4;
    const int cb4 = g4i * 4;           // 4-col sub-offset of this lane's outputs

    // ---- layer 1: h1 = relu(x @ ew0 + b0); wave wv owns cols [wv*16,+16)
    {
        f32x4 acc[4] = {};
        const f16_t* bw = pw;                       // ew0 (NT=16)
        #pragma unroll
        for (int ks = 0; ks < 12; ++ks) {
            f16x8 wa = *reinterpret_cast<const f16x8*>(
                &bw[((size_t)(ks * 16 + wv) * 64 + lane) * 8]);
            #pragma unroll
            for (int et = 0; et < 4; ++et) {
                f16x8 xb = *reinterpret_cast<const f16x8*>(
                    &X[(et * 16 + r16) * 392 + ks * 32 + g4i * 8]);
                acc[et] = MFMA16(wa, xb, acc[et]);
            }
        }
        __syncthreads();   // all stride-392 reads done before overwrite
        int cb = wv * 16 + cb4;
        float4 bs = *reinterpret_cast<const float4*>(&b0[cb]);
        float bias[4] = { bfr(bs.x), bfr(bs.y), bfr(bs.z), bfr(bs.w) };
        #pragma unroll
        for (int et = 0; et < 4; ++et) {
            f16x4 hv;
            #pragma unroll
            for (int qi = 0; qi < 4; ++qi)
                hv[qi] = (f16_t)fmaxf(acc[et][qi] + bias[qi], 0.f);
            *reinterpret_cast<f16x4*>(&X[(et * 16 + r16) * 264 + cb]) = hv;
        }
    }
    __syncthreads();

    // ---- layer 2: h2 = relu(h1 @ ew1 + b1) (same buffer, stride 264)
    {
        f32x4 acc[4] = {};
        const f16_t* bw = pw + 98304;               // ew1 (NT=16)
        #pragma unroll
        for (int ks = 0; ks < 8; ++ks) {
            f16x8 wa = *reinterpret_cast<const f16x8*>(
                &bw[((size_t)(ks * 16 + wv) * 64 + lane) * 8]);
            #pragma unroll
            for (int et = 0; et < 4; ++et) {
                f16x8 xb = *reinterpret_cast<const f16x8*>(
                    &X[(et * 16 + r16) * 264 + ks * 32 + g4i * 8]);
                acc[et] = MFMA16(wa, xb, acc[et]);
            }
        }
        __syncthreads();   // all h1 reads done before overwrite
        int cb = wv * 16 + cb4;
        float4 bs = *reinterpret_cast<const float4*>(&b1[cb]);
        float bias[4] = { bfr(bs.x), bfr(bs.y), bfr(bs.z), bfr(bs.w) };
        #pragma unroll
        for (int et = 0; et < 4; ++et) {
            f16x4 hv;
            #pragma unroll
            for (int qi = 0; qi < 4; ++qi)
                hv[qi] = (f16_t)fmaxf(acc[et][qi] + bias[qi], 0.f);
            *reinterpret_cast<f16x4*>(&X[(et * 16 + r16) * 264 + cb]) = hv;
        }
    }
    __syncthreads();

    // ---- layer 3 + residual: relu(h2 @ ew2 + b2) + e @ eLin
    // wave (nh = wv&7) owns cols [nh*16,+16); (mh = wv>>3) owns edge-tiles {2mh, 2mh+1}
    {
        const int nh = wv & 7;
        const int mh = wv >> 3;
        f32x4 accF[2] = {}, accR[2] = {};
        const f16_t* bw = pw + 163840;              // ew2 (NT=8)
        #pragma unroll
        for (int ks = 0; ks < 8; ++ks) {
            f16x8 wa = *reinterpret_cast<const f16x8*>(
                &bw[((size_t)(ks * 8 + nh) * 64 + lane) * 8]);
            #pragma unroll
            for (int p = 0; p < 2; ++p) {
                f16x8 xb = *reinterpret_cast<const f16x8*>(
                    &X[((mh * 2 + p) * 16 + r16) * 264 + ks * 32 + g4i * 8]);
                accF[p] = MFMA16(wa, xb, accF[p]);
            }
        }
        const f16_t* bwL = pw + 196608;             // eLin (NT=8)
        #pragma unroll
        for (int ks = 0; ks < 4; ++ks) {
            f16x8 wa = *reinterpret_cast<const f16x8*>(
                &bwL[((size_t)(ks * 8 + nh) * 64 + lane) * 8]);
            #pragma unroll
            for (int p = 0; p < 2; ++p) {
                size_t er = ebase + (size_t)((mh * 2 + p) * 16 + r16);
                const float4* src = (const float4*)&efeat[er * 128 + ks * 32 + g4i * 8];
                float4 f0 = src[0];
                float4 f1 = src[1];
                f16x8 ebf;
                ebf[0] = (f16_t)bfr(f0.x); ebf[1] = (f16_t)bfr(f0.y);
                ebf[2] = (f16_t)bfr(f0.z); ebf[3] = (f16_t)bfr(f0.w);
                ebf[4] = (f16_t)bfr(f1.x); ebf[5] = (f16_t)bfr(f1.y);
                ebf[6] = (f16_t)bfr(f1.z); ebf[7] = (f16_t)bfr(f1.w);
                accR[p] = MFMA16(wa, ebf, accR[p]);
            }
        }
        int cb = nh * 16 + cb4;
        float4 bs = *reinterpret_cast<const float4*>(&b2[cb]);
        float bias[4] = { bfr(bs.x), bfr(bs.y), bfr(bs.z), bfr(bs.w) };
        #pragma unroll
        for (int p = 0; p < 2; ++p) {
            int rr = (mh * 2 + p) * 16 + r16;
            size_t eg2 = ebase + rr;
            float4 val;
            val.x = accR[p][0] + fmaxf(accF[p][0] + bias[0], 0.f);
            val.y = accR[p][1] + fmaxf(accF[p][1] + bias[1], 0.f);
            val.z = accR[p][2] + fmaxf(accF[p][2] + bias[2], 0.f);
            val.w = accR[p][3] + fmaxf(accF[p][3] + bias[3], 0.f);
            *reinterpret_cast<float4*>(&out_e[eg2 * 128 + cb]) = val;
            float* ap = &aggr[(size_t)cidx[rr] * 128 + cb];
            unsafeAtomicAdd(ap + 0, val.x);
            unsafeAtomicAdd(ap + 1, val.y);
            unsafeAtomicAdd(ap + 2, val.z);
            unsafeAtomicAdd(ap + 3, val.w);
        }
    }
}

// ---------------------------------------------------------------------------
// Node kernel: 32 nodes/block, 512 threads (8 waves). Swapped-operand MFMA.
// node_in = [aggr/clip(cnt) (f32, derived) | bf16(v)]; f16 mids.
// ---------------------------------------------------------------------------
__launch_bounds__(512, 6)
__global__ void node_kernel(
    const float* __restrict__ vfeat, const float* __restrict__ aggr,
    const float* __restrict__ cnts,
    const float* __restrict__ lng, const float* __restrict__ lnb,
    const f16_t* __restrict__ pw,                   // node weight base (nw0)
    const float* __restrict__ b0, const float* __restrict__ b1,
    const float* __restrict__ b2,
    float* __restrict__ out_v, int Nn)
{
    __shared__ f16_t X[32 * 264];
    __shared__ f16_t H1[32 * 264];

    const int t    = threadIdx.x;
    const int lane = t & 63;
    const int wv   = t >> 6;           // 0..7
    const size_t nbase = (size_t)blockIdx.x * 32;

    const int nl = t >> 4;
    const int pp = t & 15;
    const size_t ng = nbase + nl;
    const bool valid = ng < (size_t)Nn;

    float4 d[4];
    float s = 0.f, sq = 0.f;
    {
        float cmax = 1.f;
        if (valid) cmax = fmaxf(cnts[ng], 1.f);
        const float4* a4 = (const float4*)aggr;
        const float4* v4 = (const float4*)vfeat;
        #pragma unroll
        for (int i = 0; i < 4; ++i) {
            int q = i * 16 + pp;                   // f4 index within 64 (=256 floats)
            float4 r = make_float4(0.f, 0.f, 0.f, 0.f);
            if (valid) {
                if (q < 32) {
                    r = a4[ng * 32 + q];
                    r.x = r.x / cmax; r.y = r.y / cmax;
                    r.z = r.z / cmax; r.w = r.w / cmax;   // f32, derived — not rounded
                } else {
                    float4 rv = v4[ng * 32 + (q - 32)];
                    r.x = bfr(rv.x); r.y = bfr(rv.y); r.z = bfr(rv.z); r.w = bfr(rv.w);
                }
            }
            d[i] = r;
            s  += r.x + r.y + r.z + r.w;
            sq += r.x*r.x + r.y*r.y + r.z*r.z + r.w*r.w;
        }
    }
    #pragma unroll
    for (int off = 1; off < 16; off <<= 1) {
        s  += __shfl_xor(s, off);
        sq += __shfl_xor(sq, off);
    }
    const float mean = s * (1.f / 256.f);
    const float rstd = 1.f / sqrtf(sq * (1.f / 256.f) - mean * mean + 1e-5f);
    {
        const float4* g4p = (const float4*)lng;
        const float4* bpp = (const float4*)lnb;
        #pragma unroll
        for (int i = 0; i < 4; ++i) {
            int q = i * 16 + pp;
            float4 g = g4p[q]; float4 bb = bpp[q];
            f16x4 y;
            y[0] = (f16_t)((d[i].x - mean) * rstd * bfr(g.x) + bfr(bb.x));
            y[1] = (f16_t)((d[i].y - mean) * rstd * bfr(g.y) + bfr(bb.y));
            y[2] = (f16_t)((d[i].z - mean) * rstd * bfr(g.z) + bfr(bb.z));
            y[3] = (f16_t)((d[i].w - mean) * rstd * bfr(g.w) + bfr(bb.w));
            *reinterpret_cast<f16x4*>(&X[nl * 264 + q * 4]) = y;
        }
    }
    __syncthreads();

    const int r16 = lane & 15;
    const int g4i = lane >> 4;
    const int cb4 = g4i * 4;

    // ---- layer 1: h1 = relu(x @ nw0 + b0); wave owns cols [wv*32,+32)
    {
        f32x4 acc[2][2] = {};
        const f16_t* bw = pw;                       // nw0 (NT=16)
        #pragma unroll
        for (int ks = 0; ks < 8; ++ks) {
            f16x8 wa0 = *reinterpret_cast<const f16x8*>(
                &bw[((size_t)(ks * 16 + wv * 2 + 0) * 64 + lane) * 8]);
            f16x8 wa1 = *reinterpret_cast<const f16x8*>(
                &bw[((size_t)(ks * 16 + wv * 2 + 1) * 64 + lane) * 8]);
            #pragma unroll
            for (int nt = 0; nt < 2; ++nt) {
                f16x8 xb = *reinterpret_cast<const f16x8*>(
                    &X[(nt * 16 + r16) * 264 + ks * 32 + g4i * 8]);
                acc[nt][0] = MFMA16(wa0, xb, acc[nt][0]);
                acc[nt][1] = MFMA16(wa1, xb, acc[nt][1]);
            }
        }
        #pragma unroll
        for (int j = 0; j < 2; ++j) {
            int cb = (wv * 2 + j) * 16 + cb4;
            float4 bs = *reinterpret_cast<const float4*>(&b0[cb]);
            float bias[4] = { bfr(bs.x), bfr(bs.y), bfr(bs.z), bfr(bs.w) };
            #pragma unroll
            for (int nt = 0; nt < 2; ++nt) {
                f16x4 hv;
                #pragma unroll
                for (int qi = 0; qi < 4; ++qi)
                    hv[qi] = (f16_t)fmaxf(acc[nt][j][qi] + bias[qi], 0.f);
                *reinterpret_cast<f16x4*>(&H1[(nt * 16 + r16) * 264 + cb]) = hv;
            }
        }
    }
    __syncthreads();

    // ---- layer 2: h2 = relu(h1 @ nw1 + b1) (into X region)
    {
        f32x4 acc[2][2] = {};
        const f16_t* bw = pw + 65536;               // nw1 (NT=16)
        #pragma unroll
        for (int ks = 0; ks < 8; ++ks) {
            f16x8 wa0 = *reinterpret_cast<const f16x8*>(
                &bw[((size_t)(ks * 16 + wv * 2 + 0) * 64 + lane) * 8]);
            f16x8 wa1 = *reinterpret_cast<const f16x8*>(
                &bw[((size_t)(ks * 16 + wv * 2 + 1) * 64 + lane) * 8]);
            #pragma unroll
            for (int nt = 0; nt < 2; ++nt) {
                f16x8 xb = *reinterpret_cast<const f16x8*>(
                    &H1[(nt * 16 + r16) * 264 + ks * 32 + g4i * 8]);
                acc[nt][0] = MFMA16(wa0, xb, acc[nt][0]);
                acc[nt][1] = MFMA16(wa1, xb, acc[nt][1]);
            }
        }
        __syncthreads();   // X (LN'd input) reads all done (layer-1 barrier) — safe
        #pragma unroll
        for (int j = 0; j < 2; ++j) {
            int cb = (wv * 2 + j) * 16 + cb4;
            float4 bs = *reinterpret_cast<const float4*>(&b1[cb]);
            float bias[4] = { bfr(bs.x), bfr(bs.y), bfr(bs.z), bfr(bs.w) };
            #pragma unroll
            for (int nt = 0; nt < 2; ++nt) {
                f16x4 hv;
                #pragma unroll
                for (int qi = 0; qi < 4; ++qi)
                    hv[qi] = (f16_t)fmaxf(acc[nt][j][qi] + bias[qi], 0.f);
                *reinterpret_cast<f16x4*>(&X[(nt * 16 + r16) * 264 + cb]) = hv;
            }
        }
    }
    __syncthreads();

    // ---- layer 3 + residual: relu(h2 @ nw2 + b2) + v @ nLin; wave owns cols [wv*16,+16)
    {
        f32x4 accF[2] = {}, accR[2] = {};
        const f16_t* bw = pw + 131072;              // nw2 (NT=8)
        #pragma unroll
        for (int ks = 0; ks < 8; ++ks) {
            f16x8 wa = *reinterpret_cast<const f16x8*>(
                &bw[((size_t)(ks * 8 + wv) * 64 + lane) * 8]);
            #pragma unroll
            for (int nt = 0; nt < 2; ++nt) {
                f16x8 xb = *reinterpret_cast<const f16x8*>(
                    &X[(nt * 16 + r16) * 264 + ks * 32 + g4i * 8]);
                accF[nt] = MFMA16(wa, xb, accF[nt]);
            }
        }
        const f16_t* bwL = pw + 163840;             // nLin (NT=8)
        #pragma unroll
        for (int ks = 0; ks < 4; ++ks) {
            f16x8 wa = *reinterpret_cast<const f16x8*>(
                &bwL[((size_t)(ks * 8 + wv) * 64 + lane) * 8]);
            #pragma unroll
            for (int nt = 0; nt < 2; ++nt) {
                size_t rv = nbase + (size_t)(nt * 16 + r16);
                if (rv >= (size_t)Nn) rv = (size_t)Nn - 1;   // clamp (rows unused)
                const float4* src = (const float4*)&vfeat[rv * 128 + ks * 32 + g4i * 8];
                float4 f0 = src[0];
                float4 f1 = src[1];
                f16x8 vb;
                vb[0] = (f16_t)bfr(f0.x); vb[1] = (f16_t)bfr(f0.y);
                vb[2] = (f16_t)bfr(f0.z); vb[3] = (f16_t)bfr(f0.w);
                vb[4] = (f16_t)bfr(f1.x); vb[5] = (f16_t)bfr(f1.y);
                vb[6] = (f16_t)bfr(f1.z); vb[7] = (f16_t)bfr(f1.w);
                accR[nt] = MFMA16(wa, vb, accR[nt]);
            }
        }
        int cb = wv * 16 + cb4;
        float4 bs = *reinterpret_cast<const float4*>(&b2[cb]);
        float bias[4] = { bfr(bs.x), bfr(bs.y), bfr(bs.z), bfr(bs.w) };
        #pragma unroll
        for (int nt = 0; nt < 2; ++nt) {
            size_t ng2 = nbase + (size_t)(nt * 16 + r16);
            if (ng2 < (size_t)Nn) {
                float4 val;
                val.x = accR[nt][0] + fmaxf(accF[nt][0] + bias[0], 0.f);
                val.y = accR[nt][1] + fmaxf(accF[nt][1] + bias[1], 0.f);
                val.z = accR[nt][2] + fmaxf(accF[nt][2] + bias[2], 0.f);
                val.w = accR[nt][3] + fmaxf(accF[nt][3] + bias[3], 0.f);
                *reinterpret_cast<float4*>(&out_v[ng2 * 128 + cb]) = val;
            }
        }
    }
}

// ---------------------------------------------------------------------------
extern "C" void kernel_launch(void* const* d_in, const int* in_sizes, int n_in,
                              void* d_out, int out_size, void* d_ws, size_t ws_size,
                              hipStream_t stream)
{
    const float* v    = (const float*)d_in[0];
    const float* e    = (const float*)d_in[1];
    const int*   eidx = (const int*)d_in[2];
    const float* elng = (const float*)d_in[3];
    const float* elnb = (const float*)d_in[4];
    const float* ew0  = (const float*)d_in[5];
    const float* eb0  = (const float*)d_in[6];
    const float* ew1  = (const float*)d_in[7];
    const float* eb1  = (const float*)d_in[8];
    const float* ew2  = (const float*)d_in[9];
    const float* eb2  = (const float*)d_in[10];
    const float* eLin = (const float*)d_in[11];
    const float* nlng = (const float*)d_in[12];
    const float* nlnb = (const float*)d_in[13];
    const float* nw0  = (const float*)d_in[14];
    const float* nb0  = (const float*)d_in[15];
    const float* nw1  = (const float*)d_in[16];
    const float* nb1  = (const float*)d_in[17];
    const float* nw2  = (const float*)d_in[18];
    const float* nb2  = (const float*)d_in[19];
    const float* nLin = (const float*)d_in[20];

    const int Nn = in_sizes[0] / 128;
    const int Ee = in_sizes[1] / 128;

    float* out_v = (float*)d_out;
    float* out_e = out_v + (size_t)Nn * 128;

    float* aggr = (float*)d_ws;                       // [Nn][128] f32
    float* cnts = aggr + (size_t)Nn * 128;            // [Nn] f32
    f16_t* packw = (f16_t*)((char*)d_ws + (size_t)Nn * 129 * 4);  // 393216 f16

    hipMemsetAsync(d_ws, 0, (size_t)Nn * 129 * 4, stream);

    pack_weights_kernel<<<192, 256, 0, stream>>>(ew0, ew1, ew2, eLin,
                                                 nw0, nw1, nw2, nLin, packw);

    edge_kernel<<<(Ee + 63) / 64, 1024, 0, stream>>>(v, e, eidx, elng, elnb, packw,
                                                     eb0, eb1, eb2, out_e, aggr, cnts, Ee);

    node_kernel<<<(Nn + 31) / 32, 512, 0, stream>>>(v, aggr, cnts, nlng, nlnb,
                                                    packw + 212992, nb0, nb1, nb2,
                                                    out_v, Nn);
}

// Round 8
// 617.183 us; speedup vs baseline: 1.5069x; 1.5069x over previous
//
#include <hip/hip_runtime.h>

typedef _Float16 f16_t;
typedef f16_t f16x4 __attribute__((ext_vector_type(4)));
typedef f16_t f16x8 __attribute__((ext_vector_type(8)));
typedef float f32x4 __attribute__((ext_vector_type(4)));

// mfma_f32_16x16x32_f16 roles (verified):
//   A-frag: lane l -> A[row=l&15][k=(l>>4)*8+j]
//   B-frag: lane l -> B[k=(l>>4)*8+j][col=l&15]
//   D     : lane l -> D[row=(l>>4)*4+reg][col=l&15]
// Packed weight frag (lane l, elem j = W[k][outcol=l&15]) serves BOTH roles:
//   swapped   MFMA(W, X): D[outcol][edge] -> lane edge=l&15, 4 outcols -> b64 LDS write
//   unswapped MFMA(X, W): D[edge][outcol] -> lane outcol=l&15, 4 edges  -> coalesced global
#define MFMA16(a, b, c) __builtin_amdgcn_mfma_f32_16x16x32_f16((a), (b), (c), 0, 0, 0)

// bf16 round (RNE) — matches the reference harness's input rounding; bf16 values
// at these magnitudes are exactly representable in f16.
__device__ __forceinline__ float bfr(float x) { return (float)(__bf16)x; }

// ---------------------------------------------------------------------------
// Pack fp32 weight matrices into f16 MFMA fragment order, bf16-rounded.
// frag (kstep, ntile): lane l, elem j -> W[kstep*32 + (l>>4)*8 + j][ntile*16 + (l&15)]
// ---------------------------------------------------------------------------
__global__ void pack_weights_kernel(
    const float* __restrict__ ew0, const float* __restrict__ ew1,
    const float* __restrict__ ew2, const float* __restrict__ eL,
    const float* __restrict__ nw0, const float* __restrict__ nw1,
    const float* __restrict__ nw2, const float* __restrict__ nL,
    f16_t* __restrict__ dst)
{
    int tid = blockIdx.x * 256 + threadIdx.x;
    int fid = tid >> 6, lane = tid & 63;
    const float* src; int Ncols, foff, doff;
    if (fid < 192)      { src = ew0; Ncols = 256; foff = 0;   doff = 0;      }
    else if (fid < 320) { src = ew1; Ncols = 256; foff = 192; doff = 98304;  }
    else if (fid < 384) { src = ew2; Ncols = 128; foff = 320; doff = 163840; }
    else if (fid < 416) { src = eL;  Ncols = 128; foff = 384; doff = 196608; }
    else if (fid < 544) { src = nw0; Ncols = 256; foff = 416; doff = 212992; }
    else if (fid < 672) { src = nw1; Ncols = 256; foff = 544; doff = 278528; }
    else if (fid < 736) { src = nw2; Ncols = 128; foff = 672; doff = 344064; }
    else                { src = nL;  Ncols = 128; foff = 736; doff = 376832; }
    int f = fid - foff;
    int NT = Ncols >> 4;
    int kstep = f / NT, ntile = f - kstep * NT;
    int col = ntile * 16 + (lane & 15);
    int kbase = kstep * 32 + ((lane >> 4) << 3);
    f16x8 out;
    #pragma unroll
    for (int j = 0; j < 8; ++j)
        out[j] = (f16_t)bfr(src[(size_t)(kbase + j) * Ncols + col]);
    *reinterpret_cast<f16x8*>(dst + (size_t)doff + ((size_t)f * 64 + lane) * 8) = out;
}

// ---------------------------------------------------------------------------
// Edge kernel: 128 edges/block, 1024 threads (16 waves = rw2 x cw8), 1 block/CU.
// Single LDS X buffer reused: LN'd concat (stride 392) -> h1 (stride 264)
// -> h2 (stride 264), barrier between last-read and overwrite.
// L1/L2: swapped operands, 2 weight frags per ks (8 MFMA per 4 LDS reads).
// L3: un-swapped -> coalesced out_e stores + 64B-grouped atomics.
// ---------------------------------------------------------------------------
__launch_bounds__(1024, 4)
__global__ void edge_kernel(
    const float* __restrict__ vfeat, const float* __restrict__ efeat,
    const int* __restrict__ eidx,
    const float* __restrict__ lng, const float* __restrict__ lnb,
    const f16_t* __restrict__ pw,
    const float* __restrict__ b0, const float* __restrict__ b1,
    const float* __restrict__ b2,
    float* __restrict__ out_e, float* __restrict__ aggr, float* __restrict__ cnts,
    int Ee)
{
    __shared__ f16_t X[128 * 392];     // 100352 B, reused across layers
    __shared__ int cidx[128];

    const int t    = threadIdx.x;
    const int lane = t & 63;
    const int wv   = t >> 6;           // 0..15
    const int cw   = wv & 7;           // col-group
    const int rw   = wv >> 3;          // row-group (64 edges each)
    const size_t ebase = (size_t)blockIdx.x * 128;

    // ---- phase 0: gather + bf16-round -> f16 LDS + LN stats
    // thread (el, pp): pp-th of 8 slices of one edge row (12 float4 each)
    const int el = t >> 3;             // 0..127
    const int pp = t & 7;
    const size_t eg0 = ebase + el;
    const int r0 = eidx[eg0];
    const int c0 = eidx[(size_t)Ee + eg0];

    float s = 0.f, sq = 0.f;
    {
        const float4* e4 = (const float4*)efeat;
        const float4* v4 = (const float4*)vfeat;
        #pragma unroll
        for (int i = 0; i < 12; ++i) {
            int q = i * 8 + pp;                 // f4 index within 96 (=384 floats)
            float4 r;
            if (q < 32)      r = e4[eg0 * 32 + q];
            else if (q < 64) r = v4[(size_t)r0 * 32 + (q - 32)];
            else             r = v4[(size_t)c0 * 32 + (q - 64)];
            r.x = bfr(r.x); r.y = bfr(r.y); r.z = bfr(r.z); r.w = bfr(r.w);
            f16x4 h;
            h[0] = (f16_t)r.x; h[1] = (f16_t)r.y; h[2] = (f16_t)r.z; h[3] = (f16_t)r.w;
            *reinterpret_cast<f16x4*>(&X[el * 392 + q * 4]) = h;
            s  += r.x + r.y + r.z + r.w;
            sq += r.x*r.x + r.y*r.y + r.z*r.z + r.w*r.w;
        }
        if (pp == 0) {
            cidx[el] = c0;
            unsafeAtomicAdd(&cnts[c0], 1.0f);
        }
    }
    #pragma unroll
    for (int off = 1; off < 8; off <<= 1) {
        s  += __shfl_xor(s, off);
        sq += __shfl_xor(sq, off);
    }
    const float mean = s * (1.f / 384.f);
    const float rstd = 1.f / sqrtf(sq * (1.f / 384.f) - mean * mean + 1e-5f);

    // ---- phase 1: normalize in place (same thread, same addresses -> ordered)
    {
        const float4* g4p = (const float4*)lng;
        const float4* bpp = (const float4*)lnb;
        #pragma unroll
        for (int i = 0; i < 12; ++i) {
            int q = i * 8 + pp;
            f16x4 h = *reinterpret_cast<f16x4*>(&X[el * 392 + q * 4]);
            float4 g = g4p[q]; float4 bb = bpp[q];
            h[0] = (f16_t)(((float)h[0] - mean) * rstd * bfr(g.x) + bfr(bb.x));
            h[1] = (f16_t)(((float)h[1] - mean) * rstd * bfr(g.y) + bfr(bb.y));
            h[2] = (f16_t)(((float)h[2] - mean) * rstd * bfr(g.z) + bfr(bb.z));
            h[3] = (f16_t)(((float)h[3] - mean) * rstd * bfr(g.w) + bfr(bb.w));
            *reinterpret_cast<f16x4*>(&X[el * 392 + q * 4]) = h;
        }
    }
    __syncthreads();

    const int r16 = lane & 15;
    const int g4i = lane >> 4;
    const int cb4 = g4i * 4;

    // ---- layer 1 (swapped): h1 = relu(x @ ew0 + b0)
    // wave (rw,cw): edges [rw*64,+64) (4 et tiles), cols [cw*32,+32) (2 frags)
    {
        f32x4 acc[4][2] = {};
        const f16_t* bw = pw;                       // ew0 (NT=16)
        #pragma unroll
        for (int ks = 0; ks < 12; ++ks) {
            f16x8 wa0 = *reinterpret_cast<const f16x8*>(
                &bw[((size_t)(ks * 16 + cw * 2 + 0) * 64 + lane) * 8]);
            f16x8 wa1 = *reinterpret_cast<const f16x8*>(
                &bw[((size_t)(ks * 16 + cw * 2 + 1) * 64 + lane) * 8]);
            #pragma unroll
            for (int et = 0; et < 4; ++et) {
                f16x8 xb = *reinterpret_cast<const f16x8*>(
                    &X[(rw * 64 + et * 16 + r16) * 392 + ks * 32 + g4i * 8]);
                acc[et][0] = MFMA16(wa0, xb, acc[et][0]);
                acc[et][1] = MFMA16(wa1, xb, acc[et][1]);
            }
        }
        __syncthreads();   // all stride-392 reads done before overwrite
        #pragma unroll
        for (int j = 0; j < 2; ++j) {
            int cb = cw * 32 + j * 16 + cb4;
            float4 bs = *reinterpret_cast<const float4*>(&b0[cb]);
            float bias[4] = { bfr(bs.x), bfr(bs.y), bfr(bs.z), bfr(bs.w) };
            #pragma unroll
            for (int et = 0; et < 4; ++et) {
                int edge = rw * 64 + et * 16 + r16;
                f16x4 hv;
                #pragma unroll
                for (int qi = 0; qi < 4; ++qi)
                    hv[qi] = (f16_t)fmaxf(acc[et][j][qi] + bias[qi], 0.f);
                *reinterpret_cast<f16x4*>(&X[edge * 264 + cb]) = hv;
            }
        }
    }
    __syncthreads();

    // ---- layer 2 (swapped): h2 = relu(h1 @ ew1 + b1), in place (stride 264)
    {
        f32x4 acc[4][2] = {};
        const f16_t* bw = pw + 98304;               // ew1 (NT=16)
        #pragma unroll
        for (int ks = 0; ks < 8; ++ks) {
            f16x8 wa0 = *reinterpret_cast<const f16x8*>(
                &bw[((size_t)(ks * 16 + cw * 2 + 0) * 64 + lane) * 8]);
            f16x8 wa1 = *reinterpret_cast<const f16x8*>(
                &bw[((size_t)(ks * 16 + cw * 2 + 1) * 64 + lane) * 8]);
            #pragma unroll
            for (int et = 0; et < 4; ++et) {
                f16x8 xb = *reinterpret_cast<const f16x8*>(
                    &X[(rw * 64 + et * 16 + r16) * 264 + ks * 32 + g4i * 8]);
                acc[et][0] = MFMA16(wa0, xb, acc[et][0]);
                acc[et][1] = MFMA16(wa1, xb, acc[et][1]);
            }
        }
        __syncthreads();   // all h1 reads done before overwrite
        #pragma unroll
        for (int j = 0; j < 2; ++j) {
            int cb = cw * 32 + j * 16 + cb4;
            float4 bs = *reinterpret_cast<const float4*>(&b1[cb]);
            float bias[4] = { bfr(bs.x), bfr(bs.y), bfr(bs.z), bfr(bs.w) };
            #pragma unroll
            for (int et = 0; et < 4; ++et) {
                int edge = rw * 64 + et * 16 + r16;
                f16x4 hv;
                #pragma unroll
                for (int qi = 0; qi < 4; ++qi)
                    hv[qi] = (f16_t)fmaxf(acc[et][j][qi] + bias[qi], 0.f);
                *reinterpret_cast<f16x4*>(&X[edge * 264 + cb]) = hv;
            }
        }
    }
    __syncthreads();

    // ---- layer 3 + residual (UN-swapped): relu(h2 @ ew2 + b2) + e @ eLin
    // wave (rw,cw): edges [rw*64,+64), cols [cw*16,+16)
    {
        f32x4 accF[4] = {}, accR[4] = {};
        const f16_t* bw = pw + 163840;              // ew2 (NT=8)
        #pragma unroll
        for (int ks = 0; ks < 8; ++ks) {
            f16x8 wb = *reinterpret_cast<const f16x8*>(
                &bw[((size_t)(ks * 8 + cw) * 64 + lane) * 8]);
            #pragma unroll
            for (int et = 0; et < 4; ++et) {
                f16x8 xa = *reinterpret_cast<const f16x8*>(
                    &X[(rw * 64 + et * 16 + r16) * 264 + ks * 32 + g4i * 8]);
                accF[et] = MFMA16(xa, wb, accF[et]);
            }
        }
        const f16_t* bwL = pw + 196608;             // eLin (NT=8)
        #pragma unroll
        for (int ks = 0; ks < 4; ++ks) {
            f16x8 wb = *reinterpret_cast<const f16x8*>(
                &bwL[((size_t)(ks * 8 + cw) * 64 + lane) * 8]);
            #pragma unroll
            for (int et = 0; et < 4; ++et) {
                size_t er = ebase + (size_t)(rw * 64 + et * 16 + r16);
                const float4* src = (const float4*)&efeat[er * 128 + ks * 32 + g4i * 8];
                float4 f0 = src[0];
                float4 f1 = src[1];
                f16x8 ea;
                ea[0] = (f16_t)bfr(f0.x); ea[1] = (f16_t)bfr(f0.y);
                ea[2] = (f16_t)bfr(f0.z); ea[3] = (f16_t)bfr(f0.w);
                ea[4] = (f16_t)bfr(f1.x); ea[5] = (f16_t)bfr(f1.y);
                ea[6] = (f16_t)bfr(f1.z); ea[7] = (f16_t)bfr(f1.w);
                accR[et] = MFMA16(ea, wb, accR[et]);
            }
        }
        int c = cw * 16 + r16;
        float bias = bfr(b2[c]);
        #pragma unroll
        for (int et = 0; et < 4; ++et)
            #pragma unroll
            for (int qi = 0; qi < 4; ++qi) {
                int rr = rw * 64 + et * 16 + cb4 + qi;
                float val = accR[et][qi] + fmaxf(accF[et][qi] + bias, 0.f);
                size_t eg2 = ebase + rr;
                out_e[eg2 * 128 + c] = val;                        // 16 consec cols/qw
                unsafeAtomicAdd(&aggr[(size_t)cidx[rr] * 128 + c], val);  // 64B group
            }
    }
}

// ---------------------------------------------------------------------------
// Node kernel: 32 nodes/block, 512 threads (8 waves). Swapped-operand MFMA for
// LDS epilogues; coalesced float4 final stores (non-atomic, per-row 16B ok).
// node_in = [aggr/clip(cnt) (f32, derived) | bf16(v)]; f16 mids.
// ---------------------------------------------------------------------------
__launch_bounds__(512, 6)
__global__ void node_kernel(
    const float* __restrict__ vfeat, const float* __restrict__ aggr,
    const float* __restrict__ cnts,
    const float* __restrict__ lng, const float* __restrict__ lnb,
    const f16_t* __restrict__ pw,                   // node weight base (nw0)
    const float* __restrict__ b0, const float* __restrict__ b1,
    const float* __restrict__ b2,
    float* __restrict__ out_v, int Nn)
{
    __shared__ f16_t X[32 * 264];
    __shared__ f16_t H1[32 * 264];

    const int t    = threadIdx.x;
    const int lane = t & 63;
    const int wv   = t >> 6;           // 0..7
    const size_t nbase = (size_t)blockIdx.x * 32;

    const int nl = t >> 4;
    const int pp = t & 15;
    const size_t ng = nbase + nl;
    const bool valid = ng < (size_t)Nn;

    float4 d[4];
    float s = 0.f, sq = 0.f;
    {
        float cmax = 1.f;
        if (valid) cmax = fmaxf(cnts[ng], 1.f);
        const float4* a4 = (const float4*)aggr;
        const float4* v4 = (const float4*)vfeat;
        #pragma unroll
        for (int i = 0; i < 4; ++i) {
            int q = i * 16 + pp;                   // f4 index within 64 (=256 floats)
            float4 r = make_float4(0.f, 0.f, 0.f, 0.f);
            if (valid) {
                if (q < 32) {
                    r = a4[ng * 32 + q];
                    r.x = r.x / cmax; r.y = r.y / cmax;
                    r.z = r.z / cmax; r.w = r.w / cmax;   // f32, derived — not rounded
                } else {
                    float4 rv = v4[ng * 32 + (q - 32)];
                    r.x = bfr(rv.x); r.y = bfr(rv.y); r.z = bfr(rv.z); r.w = bfr(rv.w);
                }
            }
            d[i] = r;
            s  += r.x + r.y + r.z + r.w;
            sq += r.x*r.x + r.y*r.y + r.z*r.z + r.w*r.w;
        }
    }
    #pragma unroll
    for (int off = 1; off < 16; off <<= 1) {
        s  += __shfl_xor(s, off);
        sq += __shfl_xor(sq, off);
    }
    const float mean = s * (1.f / 256.f);
    const float rstd = 1.f / sqrtf(sq * (1.f / 256.f) - mean * mean + 1e-5f);
    {
        const float4* g4p = (const float4*)lng;
        const float4* bpp = (const float4*)lnb;
        #pragma unroll
        for (int i = 0; i < 4; ++i) {
            int q = i * 16 + pp;
            float4 g = g4p[q]; float4 bb = bpp[q];
            f16x4 y;
            y[0] = (f16_t)((d[i].x - mean) * rstd * bfr(g.x) + bfr(bb.x));
            y[1] = (f16_t)((d[i].y - mean) * rstd * bfr(g.y) + bfr(bb.y));
            y[2] = (f16_t)((d[i].z - mean) * rstd * bfr(g.z) + bfr(bb.z));
            y[3] = (f16_t)((d[i].w - mean) * rstd * bfr(g.w) + bfr(bb.w));
            *reinterpret_cast<f16x4*>(&X[nl * 264 + q * 4]) = y;
        }
    }
    __syncthreads();

    const int r16 = lane & 15;
    const int g4i = lane >> 4;
    const int cb4 = g4i * 4;

    // ---- layer 1 (swapped): h1 = relu(x @ nw0 + b0); wave owns cols [wv*32,+32)
    {
        f32x4 acc[2][2] = {};
        const f16_t* bw = pw;                       // nw0 (NT=16)
        #pragma unroll
        for (int ks = 0; ks < 8; ++ks) {
            f16x8 wa0 = *reinterpret_cast<const f16x8*>(
                &bw[((size_t)(ks * 16 + wv * 2 + 0) * 64 + lane) * 8]);
            f16x8 wa1 = *reinterpret_cast<const f16x8*>(
                &bw[((size_t)(ks * 16 + wv * 2 + 1) * 64 + lane) * 8]);
            #pragma unroll
            for (int nt = 0; nt < 2; ++nt) {
                f16x8 xb = *reinterpret_cast<const f16x8*>(
                    &X[(nt * 16 + r16) * 264 + ks * 32 + g4i * 8]);
                acc[nt][0] = MFMA16(wa0, xb, acc[nt][0]);
                acc[nt][1] = MFMA16(wa1, xb, acc[nt][1]);
            }
        }
        #pragma unroll
        for (int j = 0; j < 2; ++j) {
            int cb = (wv * 2 + j) * 16 + cb4;
            float4 bs = *reinterpret_cast<const float4*>(&b0[cb]);
            float bias[4] = { bfr(bs.x), bfr(bs.y), bfr(bs.z), bfr(bs.w) };
            #pragma unroll
            for (int nt = 0; nt < 2; ++nt) {
                f16x4 hv;
                #pragma unroll
                for (int qi = 0; qi < 4; ++qi)
                    hv[qi] = (f16_t)fmaxf(acc[nt][j][qi] + bias[qi], 0.f);
                *reinterpret_cast<f16x4*>(&H1[(nt * 16 + r16) * 264 + cb]) = hv;
            }
        }
    }
    __syncthreads();

    // ---- layer 2 (swapped): h2 = relu(h1 @ nw1 + b1) (into X region)
    {
        f32x4 acc[2][2] = {};
        const f16_t* bw = pw + 65536;               // nw1 (NT=16)
        #pragma unroll
        for (int ks = 0; ks < 8; ++ks) {
            f16x8 wa0 = *reinterpret_cast<const f16x8*>(
                &bw[((size_t)(ks * 16 + wv * 2 + 0) * 64 + lane) * 8]);
            f16x8 wa1 = *reinterpret_cast<const f16x8*>(
                &bw[((size_t)(ks * 16 + wv * 2 + 1) * 64 + lane) * 8]);
            #pragma unroll
            for (int nt = 0; nt < 2; ++nt) {
                f16x8 xb = *reinterpret_cast<const f16x8*>(
                    &H1[(nt * 16 + r16) * 264 + ks * 32 + g4i * 8]);
                acc[nt][0] = MFMA16(wa0, xb, acc[nt][0]);
                acc[nt][1] = MFMA16(wa1, xb, acc[nt][1]);
            }
        }
        __syncthreads();
        #pragma unroll
        for (int j = 0; j < 2; ++j) {
            int cb = (wv * 2 + j) * 16 + cb4;
            float4 bs = *reinterpret_cast<const float4*>(&b1[cb]);
            float bias[4] = { bfr(bs.x), bfr(bs.y), bfr(bs.z), bfr(bs.w) };
            #pragma unroll
            for (int nt = 0; nt < 2; ++nt) {
                f16x4 hv;
                #pragma unroll
                for (int qi = 0; qi < 4; ++qi)
                    hv[qi] = (f16_t)fmaxf(acc[nt][j][qi] + bias[qi], 0.f);
                *reinterpret_cast<f16x4*>(&X[(nt * 16 + r16) * 264 + cb]) = hv;
            }
        }
    }
    __syncthreads();

    // ---- layer 3 + residual (UN-swapped): relu(h2 @ nw2 + b2) + v @ nLin
    // wave owns cols [wv*16,+16)
    {
        f32x4 accF[2] = {}, accR[2] = {};
        const f16_t* bw = pw + 131072;              // nw2 (NT=8)
        #pragma unroll
        for (int ks = 0; ks < 8; ++ks) {
            f16x8 wb = *reinterpret_cast<const f16x8*>(
                &bw[((size_t)(ks * 8 + wv) * 64 + lane) * 8]);
            #pragma unroll
            for (int nt = 0; nt < 2; ++nt) {
                f16x8 xa = *reinterpret_cast<const f16x8*>(
                    &X[(nt * 16 + r16) * 264 + ks * 32 + g4i * 8]);
                accF[nt] = MFMA16(xa, wb, accF[nt]);
            }
        }
        const f16_t* bwL = pw + 163840;             // nLin (NT=8)
        #pragma unroll
        for (int ks = 0; ks < 4; ++ks) {
            f16x8 wb = *reinterpret_cast<const f16x8*>(
                &bwL[((size_t)(ks * 8 + wv) * 64 + lane) * 8]);
            #pragma unroll
            for (int nt = 0; nt < 2; ++nt) {
                size_t rv = nbase + (size_t)(nt * 16 + r16);
                if (rv >= (size_t)Nn) rv = (size_t)Nn - 1;   // clamp (rows unused)
                const float4* src = (const float4*)&vfeat[rv * 128 + ks * 32 + g4i * 8];
                float4 f0 = src[0];
                float4 f1 = src[1];
                f16x8 va;
                va[0] = (f16_t)bfr(f0.x); va[1] = (f16_t)bfr(f0.y);
                va[2] = (f16_t)bfr(f0.z); va[3] = (f16_t)bfr(f0.w);
                va[4] = (f16_t)bfr(f1.x); va[5] = (f16_t)bfr(f1.y);
                va[6] = (f16_t)bfr(f1.z); va[7] = (f16_t)bfr(f1.w);
                accR[nt] = MFMA16(va, wb, accR[nt]);
            }
        }
        int c = wv * 16 + r16;
        float bias = bfr(b2[c]);
        #pragma unroll
        for (int nt = 0; nt < 2; ++nt)
            #pragma unroll
            for (int qi = 0; qi < 4; ++qi) {
                int rr = nt * 16 + cb4 + qi;
                size_t ng2 = nbase + rr;
                if (ng2 < (size_t)Nn) {
                    float val = accR[nt][qi] + fmaxf(accF[nt][qi] + bias, 0.f);
                    out_v[ng2 * 128 + c] = val;
                }
            }
    }
}

// ---------------------------------------------------------------------------
extern "C" void kernel_launch(void* const* d_in, const int* in_sizes, int n_in,
                              void* d_out, int out_size, void* d_ws, size_t ws_size,
                              hipStream_t stream)
{
    const float* v    = (const float*)d_in[0];
    const float* e    = (const float*)d_in[1];
    const int*   eidx = (const int*)d_in[2];
    const float* elng = (const float*)d_in[3];
    const float* elnb = (const float*)d_in[4];
    const float* ew0  = (const float*)d_in[5];
    const float* eb0  = (const float*)d_in[6];
    const float* ew1  = (const float*)d_in[7];
    const float* eb1  = (const float*)d_in[8];
    const float* ew2  = (const float*)d_in[9];
    const float* eb2  = (const float*)d_in[10];
    const float* eLin = (const float*)d_in[11];
    const float* nlng = (const float*)d_in[12];
    const float* nlnb = (const float*)d_in[13];
    const float* nw0  = (const float*)d_in[14];
    const float* nb0  = (const float*)d_in[15];
    const float* nw1  = (const float*)d_in[16];
    const float* nb1  = (const float*)d_in[17];
    const float* nw2  = (const float*)d_in[18];
    const float* nb2  = (const float*)d_in[19];
    const float* nLin = (const float*)d_in[20];

    const int Nn = in_sizes[0] / 128;
    const int Ee = in_sizes[1] / 128;

    float* out_v = (float*)d_out;
    float* out_e = out_v + (size_t)Nn * 128;

    float* aggr = (float*)d_ws;                       // [Nn][128] f32
    float* cnts = aggr + (size_t)Nn * 128;            // [Nn] f32
    f16_t* packw = (f16_t*)((char*)d_ws + (size_t)Nn * 129 * 4);  // 393216 f16

    hipMemsetAsync(d_ws, 0, (size_t)Nn * 129 * 4, stream);

    pack_weights_kernel<<<192, 256, 0, stream>>>(ew0, ew1, ew2, eLin,
                                                 nw0, nw1, nw2, nLin, packw);

    edge_kernel<<<(Ee + 127) / 128, 1024, 0, stream>>>(v, e, eidx, elng, elnb, packw,
                                                       eb0, eb1, eb2, out_e, aggr, cnts, Ee);

    node_kernel<<<(Nn + 31) / 32, 512, 0, stream>>>(v, aggr, cnts, nlng, nlnb,
                                                    packw + 212992, nb0, nb1, nb2,
                                                    out_v, Nn);
}

// Round 9
// 483.294 us; speedup vs baseline: 1.9244x; 1.2770x over previous
//
#include <hip/hip_runtime.h>

typedef _Float16 f16_t;
typedef f16_t f16x4 __attribute__((ext_vector_type(4)));
typedef f16_t f16x8 __attribute__((ext_vector_type(8)));
typedef float f32x4 __attribute__((ext_vector_type(4)));

// mfma_f32_16x16x32_f16 fragment mapping (both A and B): lane l, elem j ->
//   A[row = l&15][k = (l>>4)*8 + j]   /   B[k = (l>>4)*8 + j][col = l&15]
// D: lane l -> D[row = (l>>4)*4 + reg][col = l&15]
// A 1KB "frag" storing M[k][x] at lane = (x&15)+16*((k&31)>>3), elem j = k&7
// serves as A-frag (row = x) AND as B-frag (col = x) identically.
#define MFMA16(a, b, c) __builtin_amdgcn_mfma_f32_16x16x32_f16((a), (b), (c), 0, 0, 0)

// bf16 round (RNE) — matches the reference harness's input rounding; bf16 values
// at these magnitudes are exactly representable in f16.
__device__ __forceinline__ float bfr(float x) { return (float)(__bf16)x; }

// ---------------------------------------------------------------------------
// Pack fp32 weight matrices into f16 MFMA fragment order, bf16-rounded.
// frag (kstep, ntile): lane l, elem j -> W[kstep*32 + (l>>4)*8 + j][ntile*16 + (l&15)]
// ---------------------------------------------------------------------------
__global__ void pack_weights_kernel(
    const float* __restrict__ ew0, const float* __restrict__ ew1,
    const float* __restrict__ ew2, const float* __restrict__ eL,
    const float* __restrict__ nw0, const float* __restrict__ nw1,
    const float* __restrict__ nw2, const float* __restrict__ nL,
    f16_t* __restrict__ dst)
{
    int tid = blockIdx.x * 256 + threadIdx.x;
    int fid = tid >> 6, lane = tid & 63;
    const float* src; int Ncols, foff, doff;
    if (fid < 192)      { src = ew0; Ncols = 256; foff = 0;   doff = 0;      }
    else if (fid < 320) { src = ew1; Ncols = 256; foff = 192; doff = 98304;  }
    else if (fid < 384) { src = ew2; Ncols = 128; foff = 320; doff = 163840; }
    else if (fid < 416) { src = eL;  Ncols = 128; foff = 384; doff = 196608; }
    else if (fid < 544) { src = nw0; Ncols = 256; foff = 416; doff = 212992; }
    else if (fid < 672) { src = nw1; Ncols = 256; foff = 544; doff = 278528; }
    else if (fid < 736) { src = nw2; Ncols = 128; foff = 672; doff = 344064; }
    else                { src = nL;  Ncols = 128; foff = 736; doff = 376832; }
    int f = fid - foff;
    int NT = Ncols >> 4;
    int kstep = f / NT, ntile = f - kstep * NT;
    int col = ntile * 16 + (lane & 15);
    int kbase = kstep * 32 + ((lane >> 4) << 3);
    f16x8 out;
    #pragma unroll
    for (int j = 0; j < 8; ++j)
        out[j] = (f16_t)bfr(src[(size_t)(kbase + j) * Ncols + col]);
    *reinterpret_cast<f16x8*>(dst + (size_t)doff + ((size_t)f * 64 + lane) * 8) = out;
}

// ---------------------------------------------------------------------------
// Edge kernel: 64 edges/block, 1024 threads (16 waves = rw2 x cw8), 2 blocks/CU.
// LDS in FRAGMENT-LINEAR layout: XF = 12x4 frags (48KB) for LN'd concat,
// reused as 8x4 h1/h2 frags (32KB); ERF = 4x4 frags (16KB) raw bf16 e.
// All MFMA LDS reads are base+lane*16B (conflict-free). L1/L2 swapped
// (2 W-frags/wave -> 2 MFMA per X read, b64 frag epilogue writes);
// L3 un-swapped -> coalesced out_e + 64B-grouped atomics.
// ---------------------------------------------------------------------------
__launch_bounds__(1024, 8)
__global__ void edge_kernel(
    const float* __restrict__ vfeat, const float* __restrict__ efeat,
    const int* __restrict__ eidx,
    const float* __restrict__ lng, const float* __restrict__ lnb,
    const f16_t* __restrict__ pw,
    const float* __restrict__ b0, const float* __restrict__ b1,
    const float* __restrict__ b2,
    float* __restrict__ out_e, float* __restrict__ aggr, float* __restrict__ cnts,
    int Ee)
{
    __shared__ f16_t XF[24576];    // 48KB: [ks 0..11][et 0..3] frags of 512 f16
    __shared__ f16_t ERF[8192];    // 16KB: [ks 0..3][et 0..3] frags (raw e)
    __shared__ int cidx[64];

    const int t    = threadIdx.x;
    const int lane = t & 63;
    const int wv   = t >> 6;       // 0..15
    const int cw   = wv & 7;
    const int rw   = wv >> 3;
    const size_t ebase = (size_t)blockIdx.x * 64;

    // ---- phase 0: gather + bf16-round -> f16 frags + LN stats
    // thread (el, pp): pp-th of 16 slices of one edge row (6 float4 each)
    const int el = t >> 4;         // 0..63
    const int pp = t & 15;
    const int et0 = el >> 4;
    const size_t eg0 = ebase + el;
    const int r0 = eidx[eg0];
    const int c0 = eidx[(size_t)Ee + eg0];

    float s = 0.f, sq = 0.f;
    {
        const float4* e4 = (const float4*)efeat;
        const float4* v4 = (const float4*)vfeat;
        #pragma unroll
        for (int i = 0; i < 6; ++i) {
            int q = i * 16 + pp;              // f4 index within 96 (k = 4q..4q+3)
            float4 r;
            if (q < 32)      r = e4[eg0 * 32 + q];
            else if (q < 64) r = v4[(size_t)r0 * 32 + (q - 32)];
            else             r = v4[(size_t)c0 * 32 + (q - 64)];
            r.x = bfr(r.x); r.y = bfr(r.y); r.z = bfr(r.z); r.w = bfr(r.w);
            f16x4 h;
            h[0] = (f16_t)r.x; h[1] = (f16_t)r.y; h[2] = (f16_t)r.z; h[3] = (f16_t)r.w;
            int lanep = (el & 15) + 16 * ((q & 7) >> 1);
            int idx = ((q >> 3) * 4 + et0) * 512 + lanep * 8 + (q & 1) * 4;
            *reinterpret_cast<f16x4*>(&XF[idx]) = h;
            if (q < 32)
                *reinterpret_cast<f16x4*>(&ERF[idx]) = h;   // same formula, ks 0..3
            s  += r.x + r.y + r.z + r.w;
            sq += r.x*r.x + r.y*r.y + r.z*r.z + r.w*r.w;
        }
        if (pp == 0) {
            cidx[el] = c0;
            unsafeAtomicAdd(&cnts[c0], 1.0f);
        }
    }
    #pragma unroll
    for (int off = 1; off < 16; off <<= 1) {
        s  += __shfl_xor(s, off);
        sq += __shfl_xor(sq, off);
    }
    const float mean = s * (1.f / 384.f);
    const float rstd = 1.f / sqrtf(sq * (1.f / 384.f) - mean * mean + 1e-5f);

    // ---- phase 1: normalize XF in place (same thread, same addresses)
    {
        const float4* g4p = (const float4*)lng;
        const float4* bpp = (const float4*)lnb;
        #pragma unroll
        for (int i = 0; i < 6; ++i) {
            int q = i * 16 + pp;
            int lanep = (el & 15) + 16 * ((q & 7) >> 1);
            int idx = ((q >> 3) * 4 + et0) * 512 + lanep * 8 + (q & 1) * 4;
            f16x4 h = *reinterpret_cast<f16x4*>(&XF[idx]);
            float4 g = g4p[q]; float4 bb = bpp[q];
            h[0] = (f16_t)(((float)h[0] - mean) * rstd * bfr(g.x) + bfr(bb.x));
            h[1] = (f16_t)(((float)h[1] - mean) * rstd * bfr(g.y) + bfr(bb.y));
            h[2] = (f16_t)(((float)h[2] - mean) * rstd * bfr(g.z) + bfr(bb.z));
            h[3] = (f16_t)(((float)h[3] - mean) * rstd * bfr(g.w) + bfr(bb.w));
            *reinterpret_cast<f16x4*>(&XF[idx]) = h;
        }
    }
    __syncthreads();

    const int r16 = lane & 15;
    const int g4i = lane >> 4;

    // ---- layer 1 (swapped): h1 = relu(x @ ew0 + b0)
    // wave (rw,cw): edge tiles {rw*2, rw*2+1}, col frags {cw*2, cw*2+1}
    {
        f32x4 acc[2][2] = {};
        const f16_t* bw = pw;                       // ew0 (NT=16)
        #pragma unroll
        for (int ks = 0; ks < 12; ++ks) {
            f16x8 wa0 = *reinterpret_cast<const f16x8*>(
                &bw[((size_t)(ks * 16 + cw * 2 + 0) * 64 + lane) * 8]);
            f16x8 wa1 = *reinterpret_cast<const f16x8*>(
                &bw[((size_t)(ks * 16 + cw * 2 + 1) * 64 + lane) * 8]);
            #pragma unroll
            for (int e2 = 0; e2 < 2; ++e2) {
                f16x8 xb = *reinterpret_cast<const f16x8*>(
                    &XF[(ks * 4 + rw * 2 + e2) * 512 + lane * 8]);
                acc[e2][0] = MFMA16(wa0, xb, acc[e2][0]);
                acc[e2][1] = MFMA16(wa1, xb, acc[e2][1]);
            }
        }
        __syncthreads();   // all L1-input reads done before overwrite
        #pragma unroll
        for (int F2 = 0; F2 < 2; ++F2) {
            int cbase = (cw * 2 + F2) * 16 + g4i * 4;      // first of 4 cols
            float4 bs = *reinterpret_cast<const float4*>(&b0[cbase]);
            float bias[4] = { bfr(bs.x), bfr(bs.y), bfr(bs.z), bfr(bs.w) };
            int lane2 = r16 + 16 * ((cbase & 31) >> 3);
            int j0 = cbase & 7;
            #pragma unroll
            for (int e2 = 0; e2 < 2; ++e2) {
                f16x4 hv;
                #pragma unroll
                for (int qi = 0; qi < 4; ++qi)
                    hv[qi] = (f16_t)fmaxf(acc[e2][F2][qi] + bias[qi], 0.f);
                int idx = ((cbase >> 5) * 4 + rw * 2 + e2) * 512 + lane2 * 8 + j0;
                *reinterpret_cast<f16x4*>(&XF[idx]) = hv;
            }
        }
    }
    __syncthreads();

    // ---- layer 2 (swapped): h2 = relu(h1 @ ew1 + b1), frags in place
    {
        f32x4 acc[2][2] = {};
        const f16_t* bw = pw + 98304;               // ew1 (NT=16)
        #pragma unroll
        for (int ks = 0; ks < 8; ++ks) {
            f16x8 wa0 = *reinterpret_cast<const f16x8*>(
                &bw[((size_t)(ks * 16 + cw * 2 + 0) * 64 + lane) * 8]);
            f16x8 wa1 = *reinterpret_cast<const f16x8*>(
                &bw[((size_t)(ks * 16 + cw * 2 + 1) * 64 + lane) * 8]);
            #pragma unroll
            for (int e2 = 0; e2 < 2; ++e2) {
                f16x8 xb = *reinterpret_cast<const f16x8*>(
                    &XF[(ks * 4 + rw * 2 + e2) * 512 + lane * 8]);
                acc[e2][0] = MFMA16(wa0, xb, acc[e2][0]);
                acc[e2][1] = MFMA16(wa1, xb, acc[e2][1]);
            }
        }
        __syncthreads();   // all h1 reads done before overwrite
        #pragma unroll
        for (int F2 = 0; F2 < 2; ++F2) {
            int cbase = (cw * 2 + F2) * 16 + g4i * 4;
            float4 bs = *reinterpret_cast<const float4*>(&b1[cbase]);
            float bias[4] = { bfr(bs.x), bfr(bs.y), bfr(bs.z), bfr(bs.w) };
            int lane2 = r16 + 16 * ((cbase & 31) >> 3);
            int j0 = cbase & 7;
            #pragma unroll
            for (int e2 = 0; e2 < 2; ++e2) {
                f16x4 hv;
                #pragma unroll
                for (int qi = 0; qi < 4; ++qi)
                    hv[qi] = (f16_t)fmaxf(acc[e2][F2][qi] + bias[qi], 0.f);
                int idx = ((cbase >> 5) * 4 + rw * 2 + e2) * 512 + lane2 * 8 + j0;
                *reinterpret_cast<f16x4*>(&XF[idx]) = hv;
            }
        }
    }
    __syncthreads();

    // ---- layer 3 + residual (UN-swapped): relu(h2 @ ew2 + b2) + e @ eLin
    // wave (rw,cw): edge tiles {rw*2, rw*2+1}, cols [cw*16,+16)
    {
        f32x4 accF[2] = {}, accR[2] = {};
        const f16_t* bw = pw + 163840;              // ew2 (NT=8)
        #pragma unroll
        for (int ks = 0; ks < 8; ++ks) {
            f16x8 wb = *reinterpret_cast<const f16x8*>(
                &bw[((size_t)(ks * 8 + cw) * 64 + lane) * 8]);
            #pragma unroll
            for (int e2 = 0; e2 < 2; ++e2) {
                f16x8 xa = *reinterpret_cast<const f16x8*>(
                    &XF[(ks * 4 + rw * 2 + e2) * 512 + lane * 8]);
                accF[e2] = MFMA16(xa, wb, accF[e2]);
            }
        }
        const f16_t* bwL = pw + 196608;             // eLin (NT=8)
        #pragma unroll
        for (int ks = 0; ks < 4; ++ks) {
            f16x8 wb = *reinterpret_cast<const f16x8*>(
                &bwL[((size_t)(ks * 8 + cw) * 64 + lane) * 8]);
            #pragma unroll
            for (int e2 = 0; e2 < 2; ++e2) {
                f16x8 ea = *reinterpret_cast<const f16x8*>(
                    &ERF[(ks * 4 + rw * 2 + e2) * 512 + lane * 8]);
                accR[e2] = MFMA16(ea, wb, accR[e2]);
            }
        }
        int c = cw * 16 + r16;
        float bias = bfr(b2[c]);
        #pragma unroll
        for (int e2 = 0; e2 < 2; ++e2)
            #pragma unroll
            for (int qi = 0; qi < 4; ++qi) {
                int rr = (rw * 2 + e2) * 16 + g4i * 4 + qi;
                float val = accR[e2][qi] + fmaxf(accF[e2][qi] + bias, 0.f);
                size_t eg2 = ebase + rr;
                out_e[eg2 * 128 + c] = val;                        // 64B/quarter-wave
                unsafeAtomicAdd(&aggr[(size_t)cidx[rr] * 128 + c], val);
            }
    }
}

// ---------------------------------------------------------------------------
// Node kernel: 32 nodes/block, 512 threads (8 waves). Swapped LDS epilogues,
// un-swapped L3 for coalesced stores. (Same as round-8 version — passed.)
// ---------------------------------------------------------------------------
__launch_bounds__(512, 6)
__global__ void node_kernel(
    const float* __restrict__ vfeat, const float* __restrict__ aggr,
    const float* __restrict__ cnts,
    const float* __restrict__ lng, const float* __restrict__ lnb,
    const f16_t* __restrict__ pw,                   // node weight base (nw0)
    const float* __restrict__ b0, const float* __restrict__ b1,
    const float* __restrict__ b2,
    float* __restrict__ out_v, int Nn)
{
    __shared__ f16_t X[32 * 264];
    __shared__ f16_t H1[32 * 264];

    const int t    = threadIdx.x;
    const int lane = t & 63;
    const int wv   = t >> 6;           // 0..7
    const size_t nbase = (size_t)blockIdx.x * 32;

    const int nl = t >> 4;
    const int pp = t & 15;
    const size_t ng = nbase + nl;
    const bool valid = ng < (size_t)Nn;

    float4 d[4];
    float s = 0.f, sq = 0.f;
    {
        float cmax = 1.f;
        if (valid) cmax = fmaxf(cnts[ng], 1.f);
        const float4* a4 = (const float4*)aggr;
        const float4* v4 = (const float4*)vfeat;
        #pragma unroll
        for (int i = 0; i < 4; ++i) {
            int q = i * 16 + pp;
            float4 r = make_float4(0.f, 0.f, 0.f, 0.f);
            if (valid) {
                if (q < 32) {
                    r = a4[ng * 32 + q];
                    r.x = r.x / cmax; r.y = r.y / cmax;
                    r.z = r.z / cmax; r.w = r.w / cmax;
                } else {
                    float4 rv = v4[ng * 32 + (q - 32)];
                    r.x = bfr(rv.x); r.y = bfr(rv.y); r.z = bfr(rv.z); r.w = bfr(rv.w);
                }
            }
            d[i] = r;
            s  += r.x + r.y + r.z + r.w;
            sq += r.x*r.x + r.y*r.y + r.z*r.z + r.w*r.w;
        }
    }
    #pragma unroll
    for (int off = 1; off < 16; off <<= 1) {
        s  += __shfl_xor(s, off);
        sq += __shfl_xor(sq, off);
    }
    const float mean = s * (1.f / 256.f);
    const float rstd = 1.f / sqrtf(sq * (1.f / 256.f) - mean * mean + 1e-5f);
    {
        const float4* g4p = (const float4*)lng;
        const float4* bpp = (const float4*)lnb;
        #pragma unroll
        for (int i = 0; i < 4; ++i) {
            int q = i * 16 + pp;
            float4 g = g4p[q]; float4 bb = bpp[q];
            f16x4 y;
            y[0] = (f16_t)((d[i].x - mean) * rstd * bfr(g.x) + bfr(bb.x));
            y[1] = (f16_t)((d[i].y - mean) * rstd * bfr(g.y) + bfr(bb.y));
            y[2] = (f16_t)((d[i].z - mean) * rstd * bfr(g.z) + bfr(bb.z));
            y[3] = (f16_t)((d[i].w - mean) * rstd * bfr(g.w) + bfr(bb.w));
            *reinterpret_cast<f16x4*>(&X[nl * 264 + q * 4]) = y;
        }
    }
    __syncthreads();

    const int r16 = lane & 15;
    const int g4i = lane >> 4;
    const int cb4 = g4i * 4;

    // ---- layer 1 (swapped): wave owns cols [wv*32,+32)
    {
        f32x4 acc[2][2] = {};
        const f16_t* bw = pw;                       // nw0 (NT=16)
        #pragma unroll
        for (int ks = 0; ks < 8; ++ks) {
            f16x8 wa0 = *reinterpret_cast<const f16x8*>(
                &bw[((size_t)(ks * 16 + wv * 2 + 0) * 64 + lane) * 8]);
            f16x8 wa1 = *reinterpret_cast<const f16x8*>(
                &bw[((size_t)(ks * 16 + wv * 2 + 1) * 64 + lane) * 8]);
            #pragma unroll
            for (int nt = 0; nt < 2; ++nt) {
                f16x8 xb = *reinterpret_cast<const f16x8*>(
                    &X[(nt * 16 + r16) * 264 + ks * 32 + g4i * 8]);
                acc[nt][0] = MFMA16(wa0, xb, acc[nt][0]);
                acc[nt][1] = MFMA16(wa1, xb, acc[nt][1]);
            }
        }
        #pragma unroll
        for (int j = 0; j < 2; ++j) {
            int cb = (wv * 2 + j) * 16 + cb4;
            float4 bs = *reinterpret_cast<const float4*>(&b0[cb]);
            float bias[4] = { bfr(bs.x), bfr(bs.y), bfr(bs.z), bfr(bs.w) };
            #pragma unroll
            for (int nt = 0; nt < 2; ++nt) {
                f16x4 hv;
                #pragma unroll
                for (int qi = 0; qi < 4; ++qi)
                    hv[qi] = (f16_t)fmaxf(acc[nt][j][qi] + bias[qi], 0.f);
                *reinterpret_cast<f16x4*>(&H1[(nt * 16 + r16) * 264 + cb]) = hv;
            }
        }
    }
    __syncthreads();

    // ---- layer 2 (swapped): into X region
    {
        f32x4 acc[2][2] = {};
        const f16_t* bw = pw + 65536;               // nw1 (NT=16)
        #pragma unroll
        for (int ks = 0; ks < 8; ++ks) {
            f16x8 wa0 = *reinterpret_cast<const f16x8*>(
                &bw[((size_t)(ks * 16 + wv * 2 + 0) * 64 + lane) * 8]);
            f16x8 wa1 = *reinterpret_cast<const f16x8*>(
                &bw[((size_t)(ks * 16 + wv * 2 + 1) * 64 + lane) * 8]);
            #pragma unroll
            for (int nt = 0; nt < 2; ++nt) {
                f16x8 xb = *reinterpret_cast<const f16x8*>(
                    &H1[(nt * 16 + r16) * 264 + ks * 32 + g4i * 8]);
                acc[nt][0] = MFMA16(wa0, xb, acc[nt][0]);
                acc[nt][1] = MFMA16(wa1, xb, acc[nt][1]);
            }
        }
        __syncthreads();
        #pragma unroll
        for (int j = 0; j < 2; ++j) {
            int cb = (wv * 2 + j) * 16 + cb4;
            float4 bs = *reinterpret_cast<const float4*>(&b1[cb]);
            float bias[4] = { bfr(bs.x), bfr(bs.y), bfr(bs.z), bfr(bs.w) };
            #pragma unroll
            for (int nt = 0; nt < 2; ++nt) {
                f16x4 hv;
                #pragma unroll
                for (int qi = 0; qi < 4; ++qi)
                    hv[qi] = (f16_t)fmaxf(acc[nt][j][qi] + bias[qi], 0.f);
                *reinterpret_cast<f16x4*>(&X[(nt * 16 + r16) * 264 + cb]) = hv;
            }
        }
    }
    __syncthreads();

    // ---- layer 3 + residual (UN-swapped): wave owns cols [wv*16,+16)
    {
        f32x4 accF[2] = {}, accR[2] = {};
        const f16_t* bw = pw + 131072;              // nw2 (NT=8)
        #pragma unroll
        for (int ks = 0; ks < 8; ++ks) {
            f16x8 wb = *reinterpret_cast<const f16x8*>(
                &bw[((size_t)(ks * 8 + wv) * 64 + lane) * 8]);
            #pragma unroll
            for (int nt = 0; nt < 2; ++nt) {
                f16x8 xa = *reinterpret_cast<const f16x8*>(
                    &X[(nt * 16 + r16) * 264 + ks * 32 + g4i * 8]);
                accF[nt] = MFMA16(xa, wb, accF[nt]);
            }
        }
        const f16_t* bwL = pw + 163840;             // nLin (NT=8)
        #pragma unroll
        for (int ks = 0; ks < 4; ++ks) {
            f16x8 wb = *reinterpret_cast<const f16x8*>(
                &bwL[((size_t)(ks * 8 + wv) * 64 + lane) * 8]);
            #pragma unroll
            for (int nt = 0; nt < 2; ++nt) {
                size_t rv = nbase + (size_t)(nt * 16 + r16);
                if (rv >= (size_t)Nn) rv = (size_t)Nn - 1;
                const float4* src = (const float4*)&vfeat[rv * 128 + ks * 32 + g4i * 8];
                float4 f0 = src[0];
                float4 f1 = src[1];
                f16x8 va;
                va[0] = (f16_t)bfr(f0.x); va[1] = (f16_t)bfr(f0.y);
                va[2] = (f16_t)bfr(f0.z); va[3] = (f16_t)bfr(f0.w);
                va[4] = (f16_t)bfr(f1.x); va[5] = (f16_t)bfr(f1.y);
                va[6] = (f16_t)bfr(f1.z); va[7] = (f16_t)bfr(f1.w);
                accR[nt] = MFMA16(va, wb, accR[nt]);
            }
        }
        int c = wv * 16 + r16;
        float bias = bfr(b2[c]);
        #pragma unroll
        for (int nt = 0; nt < 2; ++nt)
            #pragma unroll
            for (int qi = 0; qi < 4; ++qi) {
                int rr = nt * 16 + cb4 + qi;
                size_t ng2 = nbase + rr;
                if (ng2 < (size_t)Nn) {
                    float val = accR[nt][qi] + fmaxf(accF[nt][qi] + bias, 0.f);
                    out_v[ng2 * 128 + c] = val;
                }
            }
    }
}

// ---------------------------------------------------------------------------
extern "C" void kernel_launch(void* const* d_in, const int* in_sizes, int n_in,
                              void* d_out, int out_size, void* d_ws, size_t ws_size,
                              hipStream_t stream)
{
    const float* v    = (const float*)d_in[0];
    const float* e    = (const float*)d_in[1];
    const int*   eidx = (const int*)d_in[2];
    const float* elng = (const float*)d_in[3];
    const float* elnb = (const float*)d_in[4];
    const float* ew0  = (const float*)d_in[5];
    const float* eb0  = (const float*)d_in[6];
    const float* ew1  = (const float*)d_in[7];
    const float* eb1  = (const float*)d_in[8];
    const float* ew2  = (const float*)d_in[9];
    const float* eb2  = (const float*)d_in[10];
    const float* eLin = (const float*)d_in[11];
    const float* nlng = (const float*)d_in[12];
    const float* nlnb = (const float*)d_in[13];
    const float* nw0  = (const float*)d_in[14];
    const float* nb0  = (const float*)d_in[15];
    const float* nw1  = (const float*)d_in[16];
    const float* nb1  = (const float*)d_in[17];
    const float* nw2  = (const float*)d_in[18];
    const float* nb2  = (const float*)d_in[19];
    const float* nLin = (const float*)d_in[20];

    const int Nn = in_sizes[0] / 128;
    const int Ee = in_sizes[1] / 128;

    float* out_v = (float*)d_out;
    float* out_e = out_v + (size_t)Nn * 128;

    float* aggr = (float*)d_ws;                       // [Nn][128] f32
    float* cnts = aggr + (size_t)Nn * 128;            // [Nn] f32
    f16_t* packw = (f16_t*)((char*)d_ws + (size_t)Nn * 129 * 4);  // 393216 f16

    hipMemsetAsync(d_ws, 0, (size_t)Nn * 129 * 4, stream);

    pack_weights_kernel<<<192, 256, 0, stream>>>(ew0, ew1, ew2, eLin,
                                                 nw0, nw1, nw2, nLin, packw);

    edge_kernel<<<(Ee + 63) / 64, 1024, 0, stream>>>(v, e, eidx, elng, elnb, packw,
                                                     eb0, eb1, eb2, out_e, aggr, cnts, Ee);

    node_kernel<<<(Nn + 31) / 32, 512, 0, stream>>>(v, aggr, cnts, nlng, nlnb,
                                                    packw + 212992, nb0, nb1, nb2,
                                                    out_v, Nn);
}

// Round 10
// 446.730 us; speedup vs baseline: 2.0819x; 1.0818x over previous
//
#include <hip/hip_runtime.h>

typedef _Float16 f16_t;
typedef f16_t f16x4 __attribute__((ext_vector_type(4)));
typedef f16_t f16x8 __attribute__((ext_vector_type(8)));
typedef float f32x4 __attribute__((ext_vector_type(4)));

// mfma_f32_16x16x32_f16 fragment mapping (A and B identical): lane l, elem j ->
//   A[row=l&15][k=(l>>4)*8+j] / B[k=(l>>4)*8+j][col=l&15]
// D: lane l -> D[row=(l>>4)*4+reg][col=l&15]
// A 1KB frag storing M[k][x] at lane=(x&15)+16*((k&31)>>3), j=k&7 serves as
// A-frag (row=x) and B-frag (col=x) identically.
#define MFMA16(a, b, c) __builtin_amdgcn_mfma_f32_16x16x32_f16((a), (b), (c), 0, 0, 0)

// bf16 round (RNE) — matches reference input rounding; exactly representable in f16.
__device__ __forceinline__ float bfr(float x) { return (float)(__bf16)x; }

// ---------------------------------------------------------------------------
// Pack fp32 weights into f16 MFMA fragment order, bf16-rounded.
// frag (kstep, ntile): lane l, elem j -> W[kstep*32+(l>>4)*8+j][ntile*16+(l&15)]
// ---------------------------------------------------------------------------
__global__ void pack_weights_kernel(
    const float* __restrict__ ew0, const float* __restrict__ ew1,
    const float* __restrict__ ew2, const float* __restrict__ eL,
    const float* __restrict__ nw0, const float* __restrict__ nw1,
    const float* __restrict__ nw2, const float* __restrict__ nL,
    f16_t* __restrict__ dst)
{
    int tid = blockIdx.x * 256 + threadIdx.x;
    int fid = tid >> 6, lane = tid & 63;
    const float* src; int Ncols, foff, doff;
    if (fid < 192)      { src = ew0; Ncols = 256; foff = 0;   doff = 0;      }
    else if (fid < 320) { src = ew1; Ncols = 256; foff = 192; doff = 98304;  }
    else if (fid < 384) { src = ew2; Ncols = 128; foff = 320; doff = 163840; }
    else if (fid < 416) { src = eL;  Ncols = 128; foff = 384; doff = 196608; }
    else if (fid < 544) { src = nw0; Ncols = 256; foff = 416; doff = 212992; }
    else if (fid < 672) { src = nw1; Ncols = 256; foff = 544; doff = 278528; }
    else if (fid < 736) { src = nw2; Ncols = 128; foff = 672; doff = 344064; }
    else                { src = nL;  Ncols = 128; foff = 736; doff = 376832; }
    int f = fid - foff;
    int NT = Ncols >> 4;
    int kstep = f / NT, ntile = f - kstep * NT;
    int col = ntile * 16 + (lane & 15);
    int kbase = kstep * 32 + ((lane >> 4) << 3);
    f16x8 out;
    #pragma unroll
    for (int j = 0; j < 8; ++j)
        out[j] = (f16_t)bfr(src[(size_t)(kbase + j) * Ncols + col]);
    *reinterpret_cast<f16x8*>(dst + (size_t)doff + ((size_t)f * 64 + lane) * 8) = out;
}

// ---------------------------------------------------------------------------
// Edge kernel: 64 edges/block, 1024 threads (16 waves), 2 blocks/CU.
// Conflict-free frag-linear LDS everywhere:
//  - phase0: transposed thread map -> octets kept in regs; raw-e octet to ERF
//    at base+lane*16B (contiguous). Stats via shfl + SB cross-wave buffer.
//  - phase1: LN in regs -> 3 b128 frag writes at base+lane*16B.
//  - L1/L2: swapped MFMA, wave owns 16 cols (weight frag fetched ONCE/block),
//    b64 epilogue writes (512B-contiguous per wave-inst).
//  - L3: un-swapped -> coalesced out_e + 64B-grouped atomics.
// ---------------------------------------------------------------------------
__launch_bounds__(1024, 8)
__global__ void edge_kernel(
    const float* __restrict__ vfeat, const float* __restrict__ efeat,
    const int* __restrict__ eidx,
    const float* __restrict__ lng, const float* __restrict__ lnb,
    const f16_t* __restrict__ pw,
    const float* __restrict__ b0, const float* __restrict__ b1,
    const float* __restrict__ b2,
    float* __restrict__ out_e, float* __restrict__ aggr, float* __restrict__ cnts,
    int Ee)
{
    __shared__ f16_t XF[12 * 4 * 512];   // 48KB: X frags [ks<12][et<4]; reused h1/h2 [ks<8][et<4]
    __shared__ f16_t ERF[4 * 4 * 512];   // 16KB: raw bf16 e frags [ks<4][et<4]
    __shared__ float SB[64 * 8];         // 2KB: per-edge partial stats [edge][quad]{s,sq}
    __shared__ int cidx[64];

    const int t    = threadIdx.x;
    const int lane = t & 63;
    const int wv   = t >> 6;             // 0..15
    const int r16  = lane & 15;
    const int g4i  = lane >> 4;
    const size_t ebase = (size_t)blockIdx.x * 64;

    // ---- phase 0: transposed gather -> regs; raw-e -> ERF; partial LN stats
    const int et_  = wv >> 2;            // edge tile 0..3
    const int sq4  = wv & 3;             // slot quad 0..3
    const int edge = et_ * 16 + r16;     // 0..63
    const int slot = sq4 * 4 + g4i;      // 0..15  (slot&3 == g4i)
    const size_t eg0 = ebase + edge;
    const int r0 = eidx[eg0];
    const int c0 = eidx[(size_t)Ee + eg0];

    f16x8 oct[3];
    float s = 0.f, sq = 0.f;
    {
        const float4* e4 = (const float4*)efeat;
        const float4* v4 = (const float4*)vfeat;
        const float4* srcs[3];
        srcs[0] = &e4[eg0 * 32 + slot * 2];
        srcs[1] = &v4[(size_t)r0 * 32 + slot * 2];
        srcs[2] = &v4[(size_t)c0 * 32 + slot * 2];
        #pragma unroll
        for (int i = 0; i < 3; ++i) {
            float4 f0 = srcs[i][0];
            float4 f1 = srcs[i][1];
            float x0 = bfr(f0.x), x1 = bfr(f0.y), x2 = bfr(f0.z), x3 = bfr(f0.w);
            float x4 = bfr(f1.x), x5 = bfr(f1.y), x6 = bfr(f1.z), x7 = bfr(f1.w);
            s  += x0 + x1 + x2 + x3 + x4 + x5 + x6 + x7;
            sq += x0*x0 + x1*x1 + x2*x2 + x3*x3 + x4*x4 + x5*x5 + x6*x6 + x7*x7;
            f16x8 h;
            h[0] = (f16_t)x0; h[1] = (f16_t)x1; h[2] = (f16_t)x2; h[3] = (f16_t)x3;
            h[4] = (f16_t)x4; h[5] = (f16_t)x5; h[6] = (f16_t)x6; h[7] = (f16_t)x7;
            oct[i] = h;
        }
        // raw e octet -> ERF frag (sq4, et_): contiguous wave write
        *reinterpret_cast<f16x8*>(&ERF[(sq4 * 4 + et_) * 512 + lane * 8]) = oct[0];
        if (slot == 0) {
            cidx[edge] = c0;
            unsafeAtomicAdd(&cnts[c0], 1.0f);
        }
    }
    // reduce over the 4 g4i groups (lanes l, l^16, l^32, l^48)
    s  += __shfl_xor(s, 16);  s  += __shfl_xor(s, 32);
    sq += __shfl_xor(sq, 16); sq += __shfl_xor(sq, 32);
    if (g4i == 0)
        *reinterpret_cast<float2*>(&SB[edge * 8 + sq4 * 2]) = make_float2(s, sq);
    __syncthreads();

    // ---- phase 1: totals -> LN in regs -> write X frags
    {
        float4 p0 = *reinterpret_cast<const float4*>(&SB[edge * 8]);
        float4 p1 = *reinterpret_cast<const float4*>(&SB[edge * 8 + 4]);
        float S = p0.x + p0.z + p1.x + p1.z;
        float Q = p0.y + p0.w + p1.y + p1.w;
        const float mean = S * (1.f / 384.f);
        const float rstd = 1.f / sqrtf(Q * (1.f / 384.f) - mean * mean + 1e-5f);
        const float4* g4p = (const float4*)lng;
        const float4* bpp = (const float4*)lnb;
        #pragma unroll
        for (int i = 0; i < 3; ++i) {
            int q = (i * 16 + slot) * 2;           // float4 index of k0 = octet*8
            float4 g0 = g4p[q], g1 = g4p[q + 1];
            float4 bb0 = bpp[q], bb1 = bpp[q + 1];
            f16x8 h = oct[i];
            f16x8 y;
            y[0] = (f16_t)(((float)h[0] - mean) * rstd * bfr(g0.x) + bfr(bb0.x));
            y[1] = (f16_t)(((float)h[1] - mean) * rstd * bfr(g0.y) + bfr(bb0.y));
            y[2] = (f16_t)(((float)h[2] - mean) * rstd * bfr(g0.z) + bfr(bb0.z));
            y[3] = (f16_t)(((float)h[3] - mean) * rstd * bfr(g0.w) + bfr(bb0.w));
            y[4] = (f16_t)(((float)h[4] - mean) * rstd * bfr(g1.x) + bfr(bb1.x));
            y[5] = (f16_t)(((float)h[5] - mean) * rstd * bfr(g1.y) + bfr(bb1.y));
            y[6] = (f16_t)(((float)h[6] - mean) * rstd * bfr(g1.z) + bfr(bb1.z));
            y[7] = (f16_t)(((float)h[7] - mean) * rstd * bfr(g1.w) + bfr(bb1.w));
            int ks = i * 4 + sq4;                  // 0..11
            *reinterpret_cast<f16x8*>(&XF[(ks * 4 + et_) * 512 + lane * 8]) = y;
        }
    }
    __syncthreads();

    // ---- layer 1 (swapped): h1 = relu(x @ ew0 + b0); wave owns cols [wv*16,+16)
    {
        f32x4 acc[4] = {};
        const f16_t* bw = pw;                       // ew0 (NT=16)
        #pragma unroll
        for (int ks = 0; ks < 12; ++ks) {
            f16x8 wa = *reinterpret_cast<const f16x8*>(
                &bw[((size_t)(ks * 16 + wv) * 64 + lane) * 8]);
            #pragma unroll
            for (int et = 0; et < 4; ++et) {
                f16x8 xb = *reinterpret_cast<const f16x8*>(
                    &XF[(ks * 4 + et) * 512 + lane * 8]);
                acc[et] = MFMA16(wa, xb, acc[et]);
            }
        }
        __syncthreads();   // all X reads done before overwriting frags 0..7
        int cb = wv * 16 + g4i * 4;
        float4 bs = *reinterpret_cast<const float4*>(&b0[cb]);
        float bias[4] = { bfr(bs.x), bfr(bs.y), bfr(bs.z), bfr(bs.w) };
        int ks2 = wv >> 1;
        int lane2 = r16 + 16 * ((wv & 1) * 2 + (g4i >> 1));
        int j0 = (g4i & 1) * 4;
        #pragma unroll
        for (int et = 0; et < 4; ++et) {
            f16x4 hv;
            #pragma unroll
            for (int qi = 0; qi < 4; ++qi)
                hv[qi] = (f16_t)fmaxf(acc[et][qi] + bias[qi], 0.f);
            *reinterpret_cast<f16x4*>(&XF[(ks2 * 4 + et) * 512 + lane2 * 8 + j0]) = hv;
        }
    }
    __syncthreads();

    // ---- layer 2 (swapped): h2 = relu(h1 @ ew1 + b1), same frag scheme
    {
        f32x4 acc[4] = {};
        const f16_t* bw = pw + 98304;               // ew1 (NT=16)
        #pragma unroll
        for (int ks = 0; ks < 8; ++ks) {
            f16x8 wa = *reinterpret_cast<const f16x8*>(
                &bw[((size_t)(ks * 16 + wv) * 64 + lane) * 8]);
            #pragma unroll
            for (int et = 0; et < 4; ++et) {
                f16x8 xb = *reinterpret_cast<const f16x8*>(
                    &XF[(ks * 4 + et) * 512 + lane * 8]);
                acc[et] = MFMA16(wa, xb, acc[et]);
            }
        }
        __syncthreads();   // all h1 reads done before overwrite
        int cb = wv * 16 + g4i * 4;
        float4 bs = *reinterpret_cast<const float4*>(&b1[cb]);
        float bias[4] = { bfr(bs.x), bfr(bs.y), bfr(bs.z), bfr(bs.w) };
        int ks2 = wv >> 1;
        int lane2 = r16 + 16 * ((wv & 1) * 2 + (g4i >> 1));
        int j0 = (g4i & 1) * 4;
        #pragma unroll
        for (int et = 0; et < 4; ++et) {
            f16x4 hv;
            #pragma unroll
            for (int qi = 0; qi < 4; ++qi)
                hv[qi] = (f16_t)fmaxf(acc[et][qi] + bias[qi], 0.f);
            *reinterpret_cast<f16x4*>(&XF[(ks2 * 4 + et) * 512 + lane2 * 8 + j0]) = hv;
        }
    }
    __syncthreads();

    // ---- layer 3 + residual (UN-swapped): relu(h2 @ ew2 + b2) + e @ eLin
    // wave: cols [cw*16,+16), edge tiles {rw*2, rw*2+1}
    {
        const int cw = wv & 7;
        const int rw = wv >> 3;
        f32x4 accF[2] = {}, accR[2] = {};
        const f16_t* bw = pw + 163840;              // ew2 (NT=8)
        #pragma unroll
        for (int ks = 0; ks < 8; ++ks) {
            f16x8 wb = *reinterpret_cast<const f16x8*>(
                &bw[((size_t)(ks * 8 + cw) * 64 + lane) * 8]);
            #pragma unroll
            for (int e2 = 0; e2 < 2; ++e2) {
                f16x8 xa = *reinterpret_cast<const f16x8*>(
                    &XF[(ks * 4 + rw * 2 + e2) * 512 + lane * 8]);
                accF[e2] = MFMA16(xa, wb, accF[e2]);
            }
        }
        const f16_t* bwL = pw + 196608;             // eLin (NT=8)
        #pragma unroll
        for (int ks = 0; ks < 4; ++ks) {
            f16x8 wb = *reinterpret_cast<const f16x8*>(
                &bwL[((size_t)(ks * 8 + cw) * 64 + lane) * 8]);
            #pragma unroll
            for (int e2 = 0; e2 < 2; ++e2) {
                f16x8 ea = *reinterpret_cast<const f16x8*>(
                    &ERF[(ks * 4 + rw * 2 + e2) * 512 + lane * 8]);
                accR[e2] = MFMA16(ea, wb, accR[e2]);
            }
        }
        int c = cw * 16 + r16;
        float bias = bfr(b2[c]);
        #pragma unroll
        for (int e2 = 0; e2 < 2; ++e2)
            #pragma unroll
            for (int qi = 0; qi < 4; ++qi) {
                int rr = (rw * 2 + e2) * 16 + g4i * 4 + qi;
                float val = accR[e2][qi] + fmaxf(accF[e2][qi] + bias, 0.f);
                size_t eg2 = ebase + rr;
                out_e[eg2 * 128 + c] = val;
                unsafeAtomicAdd(&aggr[(size_t)cidx[rr] * 128 + c], val);
            }
    }
}

// ---------------------------------------------------------------------------
// Node kernel: 32 nodes/block, 512 threads (8 waves). Swapped LDS epilogues,
// un-swapped L3 coalesced stores. (Round-9 version — passed.)
// ---------------------------------------------------------------------------
__launch_bounds__(512, 6)
__global__ void node_kernel(
    const float* __restrict__ vfeat, const float* __restrict__ aggr,
    const float* __restrict__ cnts,
    const float* __restrict__ lng, const float* __restrict__ lnb,
    const f16_t* __restrict__ pw,                   // node weight base (nw0)
    const float* __restrict__ b0, const float* __restrict__ b1,
    const float* __restrict__ b2,
    float* __restrict__ out_v, int Nn)
{
    __shared__ f16_t X[32 * 264];
    __shared__ f16_t H1[32 * 264];

    const int t    = threadIdx.x;
    const int lane = t & 63;
    const int wv   = t >> 6;           // 0..7
    const size_t nbase = (size_t)blockIdx.x * 32;

    const int nl = t >> 4;
    const int pp = t & 15;
    const size_t ng = nbase + nl;
    const bool valid = ng < (size_t)Nn;

    float4 d[4];
    float s = 0.f, sq = 0.f;
    {
        float cmax = 1.f;
        if (valid) cmax = fmaxf(cnts[ng], 1.f);
        const float4* a4 = (const float4*)aggr;
        const float4* v4 = (const float4*)vfeat;
        #pragma unroll
        for (int i = 0; i < 4; ++i) {
            int q = i * 16 + pp;
            float4 r = make_float4(0.f, 0.f, 0.f, 0.f);
            if (valid) {
                if (q < 32) {
                    r = a4[ng * 32 + q];
                    r.x = r.x / cmax; r.y = r.y / cmax;
                    r.z = r.z / cmax; r.w = r.w / cmax;
                } else {
                    float4 rv = v4[ng * 32 + (q - 32)];
                    r.x = bfr(rv.x); r.y = bfr(rv.y); r.z = bfr(rv.z); r.w = bfr(rv.w);
                }
            }
            d[i] = r;
            s  += r.x + r.y + r.z + r.w;
            sq += r.x*r.x + r.y*r.y + r.z*r.z + r.w*r.w;
        }
    }
    #pragma unroll
    for (int off = 1; off < 16; off <<= 1) {
        s  += __shfl_xor(s, off);
        sq += __shfl_xor(sq, off);
    }
    const float mean = s * (1.f / 256.f);
    const float rstd = 1.f / sqrtf(sq * (1.f / 256.f) - mean * mean + 1e-5f);
    {
        const float4* g4p = (const float4*)lng;
        const float4* bpp = (const float4*)lnb;
        #pragma unroll
        for (int i = 0; i < 4; ++i) {
            int q = i * 16 + pp;
            float4 g = g4p[q]; float4 bb = bpp[q];
            f16x4 y;
            y[0] = (f16_t)((d[i].x - mean) * rstd * bfr(g.x) + bfr(bb.x));
            y[1] = (f16_t)((d[i].y - mean) * rstd * bfr(g.y) + bfr(bb.y));
            y[2] = (f16_t)((d[i].z - mean) * rstd * bfr(g.z) + bfr(bb.z));
            y[3] = (f16_t)((d[i].w - mean) * rstd * bfr(g.w) + bfr(bb.w));
            *reinterpret_cast<f16x4*>(&X[nl * 264 + q * 4]) = y;
        }
    }
    __syncthreads();

    const int r16 = lane & 15;
    const int g4i = lane >> 4;
    const int cb4 = g4i * 4;

    // ---- layer 1 (swapped): wave owns cols [wv*32,+32)
    {
        f32x4 acc[2][2] = {};
        const f16_t* bw = pw;                       // nw0 (NT=16)
        #pragma unroll
        for (int ks = 0; ks < 8; ++ks) {
            f16x8 wa0 = *reinterpret_cast<const f16x8*>(
                &bw[((size_t)(ks * 16 + wv * 2 + 0) * 64 + lane) * 8]);
            f16x8 wa1 = *reinterpret_cast<const f16x8*>(
                &bw[((size_t)(ks * 16 + wv * 2 + 1) * 64 + lane) * 8]);
            #pragma unroll
            for (int nt = 0; nt < 2; ++nt) {
                f16x8 xb = *reinterpret_cast<const f16x8*>(
                    &X[(nt * 16 + r16) * 264 + ks * 32 + g4i * 8]);
                acc[nt][0] = MFMA16(wa0, xb, acc[nt][0]);
                acc[nt][1] = MFMA16(wa1, xb, acc[nt][1]);
            }
        }
        #pragma unroll
        for (int j = 0; j < 2; ++j) {
            int cb = (wv * 2 + j) * 16 + cb4;
            float4 bs = *reinterpret_cast<const float4*>(&b0[cb]);
            float bias[4] = { bfr(bs.x), bfr(bs.y), bfr(bs.z), bfr(bs.w) };
            #pragma unroll
            for (int nt = 0; nt < 2; ++nt) {
                f16x4 hv;
                #pragma unroll
                for (int qi = 0; qi < 4; ++qi)
                    hv[qi] = (f16_t)fmaxf(acc[nt][j][qi] + bias[qi], 0.f);
                *reinterpret_cast<f16x4*>(&H1[(nt * 16 + r16) * 264 + cb]) = hv;
            }
        }
    }
    __syncthreads();

    // ---- layer 2 (swapped): into X region
    {
        f32x4 acc[2][2] = {};
        const f16_t* bw = pw + 65536;               // nw1 (NT=16)
        #pragma unroll
        for (int ks = 0; ks < 8; ++ks) {
            f16x8 wa0 = *reinterpret_cast<const f16x8*>(
                &bw[((size_t)(ks * 16 + wv * 2 + 0) * 64 + lane) * 8]);
            f16x8 wa1 = *reinterpret_cast<const f16x8*>(
                &bw[((size_t)(ks * 16 + wv * 2 + 1) * 64 + lane) * 8]);
            #pragma unroll
            for (int nt = 0; nt < 2; ++nt) {
                f16x8 xb = *reinterpret_cast<const f16x8*>(
                    &H1[(nt * 16 + r16) * 264 + ks * 32 + g4i * 8]);
                acc[nt][0] = MFMA16(wa0, xb, acc[nt][0]);
                acc[nt][1] = MFMA16(wa1, xb, acc[nt][1]);
            }
        }
        __syncthreads();
        #pragma unroll
        for (int j = 0; j < 2; ++j) {
            int cb = (wv * 2 + j) * 16 + cb4;
            float4 bs = *reinterpret_cast<const float4*>(&b1[cb]);
            float bias[4] = { bfr(bs.x), bfr(bs.y), bfr(bs.z), bfr(bs.w) };
            #pragma unroll
            for (int nt = 0; nt < 2; ++nt) {
                f16x4 hv;
                #pragma unroll
                for (int qi = 0; qi < 4; ++qi)
                    hv[qi] = (f16_t)fmaxf(acc[nt][j][qi] + bias[qi], 0.f);
                *reinterpret_cast<f16x4*>(&X[(nt * 16 + r16) * 264 + cb]) = hv;
            }
        }
    }
    __syncthreads();

    // ---- layer 3 + residual (UN-swapped): wave owns cols [wv*16,+16)
    {
        f32x4 accF[2] = {}, accR[2] = {};
        const f16_t* bw = pw + 131072;              // nw2 (NT=8)
        #pragma unroll
        for (int ks = 0; ks < 8; ++ks) {
            f16x8 wb = *reinterpret_cast<const f16x8*>(
                &bw[((size_t)(ks * 8 + wv) * 64 + lane) * 8]);
            #pragma unroll
            for (int nt = 0; nt < 2; ++nt) {
                f16x8 xa = *reinterpret_cast<const f16x8*>(
                    &X[(nt * 16 + r16) * 264 + ks * 32 + g4i * 8]);
                accF[nt] = MFMA16(xa, wb, accF[nt]);
            }
        }
        const f16_t* bwL = pw + 163840;             // nLin (NT=8)
        #pragma unroll
        for (int ks = 0; ks < 4; ++ks) {
            f16x8 wb = *reinterpret_cast<const f16x8*>(
                &bwL[((size_t)(ks * 8 + wv) * 64 + lane) * 8]);
            #pragma unroll
            for (int nt = 0; nt < 2; ++nt) {
                size_t rv = nbase + (size_t)(nt * 16 + r16);
                if (rv >= (size_t)Nn) rv = (size_t)Nn - 1;
                const float4* src = (const float4*)&vfeat[rv * 128 + ks * 32 + g4i * 8];
                float4 f0 = src[0];
                float4 f1 = src[1];
                f16x8 va;
                va[0] = (f16_t)bfr(f0.x); va[1] = (f16_t)bfr(f0.y);
                va[2] = (f16_t)bfr(f0.z); va[3] = (f16_t)bfr(f0.w);
                va[4] = (f16_t)bfr(f1.x); va[5] = (f16_t)bfr(f1.y);
                va[6] = (f16_t)bfr(f1.z); va[7] = (f16_t)bfr(f1.w);
                accR[nt] = MFMA16(va, wb, accR[nt]);
            }
        }
        int c = wv * 16 + r16;
        float bias = bfr(b2[c]);
        #pragma unroll
        for (int nt = 0; nt < 2; ++nt)
            #pragma unroll
            for (int qi = 0; qi < 4; ++qi) {
                int rr = nt * 16 + cb4 + qi;
                size_t ng2 = nbase + rr;
                if (ng2 < (size_t)Nn) {
                    float val = accR[nt][qi] + fmaxf(accF[nt][qi] + bias, 0.f);
                    out_v[ng2 * 128 + c] = val;
                }
            }
    }
}

// ---------------------------------------------------------------------------
extern "C" void kernel_launch(void* const* d_in, const int* in_sizes, int n_in,
                              void* d_out, int out_size, void* d_ws, size_t ws_size,
                              hipStream_t stream)
{
    const float* v    = (const float*)d_in[0];
    const float* e    = (const float*)d_in[1];
    const int*   eidx = (const int*)d_in[2];
    const float* elng = (const float*)d_in[3];
    const float* elnb = (const float*)d_in[4];
    const float* ew0  = (const float*)d_in[5];
    const float* eb0  = (const float*)d_in[6];
    const float* ew1  = (const float*)d_in[7];
    const float* eb1  = (const float*)d_in[8];
    const float* ew2  = (const float*)d_in[9];
    const float* eb2  = (const float*)d_in[10];
    const float* eLin = (const float*)d_in[11];
    const float* nlng = (const float*)d_in[12];
    const float* nlnb = (const float*)d_in[13];
    const float* nw0  = (const float*)d_in[14];
    const float* nb0  = (const float*)d_in[15];
    const float* nw1  = (const float*)d_in[16];
    const float* nb1  = (const float*)d_in[17];
    const float* nw2  = (const float*)d_in[18];
    const float* nb2  = (const float*)d_in[19];
    const float* nLin = (const float*)d_in[20];

    const int Nn = in_sizes[0] / 128;
    const int Ee = in_sizes[1] / 128;

    float* out_v = (float*)d_out;
    float* out_e = out_v + (size_t)Nn * 128;

    float* aggr = (float*)d_ws;                       // [Nn][128] f32
    float* cnts = aggr + (size_t)Nn * 128;            // [Nn] f32
    f16_t* packw = (f16_t*)((char*)d_ws + (size_t)Nn * 129 * 4);  // 393216 f16

    hipMemsetAsync(d_ws, 0, (size_t)Nn * 129 * 4, stream);

    pack_weights_kernel<<<192, 256, 0, stream>>>(ew0, ew1, ew2, eLin,
                                                 nw0, nw1, nw2, nLin, packw);

    edge_kernel<<<(Ee + 63) / 64, 1024, 0, stream>>>(v, e, eidx, elng, elnb, packw,
                                                     eb0, eb1, eb2, out_e, aggr, cnts, Ee);

    node_kernel<<<(Nn + 31) / 32, 512, 0, stream>>>(v, aggr, cnts, nlng, nlnb,
                                                    packw + 212992, nb0, nb1, nb2,
                                                    out_v, Nn);
}

// Round 11
// 434.681 us; speedup vs baseline: 2.1396x; 1.0277x over previous
//
#include <hip/hip_runtime.h>

typedef _Float16 f16_t;
typedef f16_t f16x4 __attribute__((ext_vector_type(4)));
typedef f16_t f16x8 __attribute__((ext_vector_type(8)));
typedef float f32x4 __attribute__((ext_vector_type(4)));

// mfma_f32_16x16x32_f16 fragment mapping (A and B identical): lane l, elem j ->
//   A[row=l&15][k=(l>>4)*8+j] / B[k=(l>>4)*8+j][col=l&15]
// D: lane l -> D[row=(l>>4)*4+reg][col=l&15]
// A 1KB frag storing M[k][x] at lane=(x&15)+16*((k&31)>>3), j=k&7 serves as
// A-frag (row=x) and B-frag (col=x) identically.
#define MFMA16(a, b, c) __builtin_amdgcn_mfma_f32_16x16x32_f16((a), (b), (c), 0, 0, 0)

// bf16 round (RNE) — matches reference input rounding; exactly representable in f16.
__device__ __forceinline__ float bfr(float x) { return (float)(__bf16)x; }

// ---------------------------------------------------------------------------
// Pack fp32 weights into f16 MFMA fragment order, bf16-rounded.
// frag (kstep, ntile): lane l, elem j -> W[kstep*32+(l>>4)*8+j][ntile*16+(l&15)]
// ---------------------------------------------------------------------------
__global__ void pack_weights_kernel(
    const float* __restrict__ ew0, const float* __restrict__ ew1,
    const float* __restrict__ ew2, const float* __restrict__ eL,
    const float* __restrict__ nw0, const float* __restrict__ nw1,
    const float* __restrict__ nw2, const float* __restrict__ nL,
    f16_t* __restrict__ dst)
{
    int tid = blockIdx.x * 256 + threadIdx.x;
    int fid = tid >> 6, lane = tid & 63;
    const float* src; int Ncols, foff, doff;
    if (fid < 192)      { src = ew0; Ncols = 256; foff = 0;   doff = 0;      }
    else if (fid < 320) { src = ew1; Ncols = 256; foff = 192; doff = 98304;  }
    else if (fid < 384) { src = ew2; Ncols = 128; foff = 320; doff = 163840; }
    else if (fid < 416) { src = eL;  Ncols = 128; foff = 384; doff = 196608; }
    else if (fid < 544) { src = nw0; Ncols = 256; foff = 416; doff = 212992; }
    else if (fid < 672) { src = nw1; Ncols = 256; foff = 544; doff = 278528; }
    else if (fid < 736) { src = nw2; Ncols = 128; foff = 672; doff = 344064; }
    else                { src = nL;  Ncols = 128; foff = 736; doff = 376832; }
    int f = fid - foff;
    int NT = Ncols >> 4;
    int kstep = f / NT, ntile = f - kstep * NT;
    int col = ntile * 16 + (lane & 15);
    int kbase = kstep * 32 + ((lane >> 4) << 3);
    f16x8 out;
    #pragma unroll
    for (int j = 0; j < 8; ++j)
        out[j] = (f16_t)bfr(src[(size_t)(kbase + j) * Ncols + col]);
    *reinterpret_cast<f16x8*>(dst + (size_t)doff + ((size_t)f * 64 + lane) * 8) = out;
}

// ---------------------------------------------------------------------------
// Pre-round LN gains/biases + layer biases to the bf16 grid (f32 storage).
// pp layout: 0 elng(384) | 384 elnb(384) | 768 eb0(256) | 1024 eb1(256)
//            1280 eb2(128) | 1408 nlng(256) | 1664 nlnb(256) | 1920 nb0(256)
//            2176 nb1(256) | 2432 nb2(128)   -> 2560 floats
// ---------------------------------------------------------------------------
__global__ void pack_params_kernel(
    const float* __restrict__ elng, const float* __restrict__ elnb,
    const float* __restrict__ eb0,  const float* __restrict__ eb1,
    const float* __restrict__ eb2,  const float* __restrict__ nlng,
    const float* __restrict__ nlnb, const float* __restrict__ nb0,
    const float* __restrict__ nb1,  const float* __restrict__ nb2,
    float* __restrict__ pp)
{
    int tid = blockIdx.x * 256 + threadIdx.x;
    if (tid >= 2560) return;
    const float* src; int off;
    if (tid < 384)       { src = elng; off = 0; }
    else if (tid < 768)  { src = elnb; off = 384; }
    else if (tid < 1024) { src = eb0;  off = 768; }
    else if (tid < 1280) { src = eb1;  off = 1024; }
    else if (tid < 1408) { src = eb2;  off = 1280; }
    else if (tid < 1664) { src = nlng; off = 1408; }
    else if (tid < 1920) { src = nlnb; off = 1664; }
    else if (tid < 2176) { src = nb0;  off = 1920; }
    else if (tid < 2432) { src = nb1;  off = 2176; }
    else                 { src = nb2;  off = 2432; }
    pp[tid] = bfr(src[tid - off]);
}

// ---------------------------------------------------------------------------
// Edge kernel: 64 edges/block, 1024 threads (16 waves), 2 blocks/CU.
// R10 conflict-free frag-linear structure + 2-deep weight prefetch +
// pre-rounded params (no bfr on g/b/bias in hot path).
// ---------------------------------------------------------------------------
__launch_bounds__(1024, 8)
__global__ void edge_kernel(
    const float* __restrict__ vfeat, const float* __restrict__ efeat,
    const int* __restrict__ eidx,
    const float* __restrict__ pp,          // pre-rounded params (edge @0..1407)
    const f16_t* __restrict__ pw,
    float* __restrict__ out_e, float* __restrict__ aggr, float* __restrict__ cnts,
    int Ee)
{
    __shared__ f16_t XF[12 * 4 * 512];   // 48KB: X frags [ks<12][et<4]; reused h1/h2
    __shared__ f16_t ERF[4 * 4 * 512];   // 16KB: raw bf16 e frags
    __shared__ float SB[64 * 8];         // 2KB: per-edge partial stats
    __shared__ int cidx[64];

    const int t    = threadIdx.x;
    const int lane = t & 63;
    const int wv   = t >> 6;             // 0..15
    const int r16  = lane & 15;
    const int g4i  = lane >> 4;
    const size_t ebase = (size_t)blockIdx.x * 64;

    // ---- phase 0: transposed gather -> regs; raw-e -> ERF; partial LN stats
    const int et_  = wv >> 2;
    const int sq4  = wv & 3;
    const int edge = et_ * 16 + r16;
    const int slot = sq4 * 4 + g4i;      // slot&3 == g4i
    const size_t eg0 = ebase + edge;
    const int r0 = eidx[eg0];
    const int c0 = eidx[(size_t)Ee + eg0];

    f16x8 oct[3];
    float s = 0.f, sq = 0.f;
    {
        const float4* e4 = (const float4*)efeat;
        const float4* v4 = (const float4*)vfeat;
        const float4* srcs[3];
        srcs[0] = &e4[eg0 * 32 + slot * 2];
        srcs[1] = &v4[(size_t)r0 * 32 + slot * 2];
        srcs[2] = &v4[(size_t)c0 * 32 + slot * 2];
        #pragma unroll
        for (int i = 0; i < 3; ++i) {
            float4 f0 = srcs[i][0];
            float4 f1 = srcs[i][1];
            float x0 = bfr(f0.x), x1 = bfr(f0.y), x2 = bfr(f0.z), x3 = bfr(f0.w);
            float x4 = bfr(f1.x), x5 = bfr(f1.y), x6 = bfr(f1.z), x7 = bfr(f1.w);
            s  += x0 + x1 + x2 + x3 + x4 + x5 + x6 + x7;
            sq += x0*x0 + x1*x1 + x2*x2 + x3*x3 + x4*x4 + x5*x5 + x6*x6 + x7*x7;
            f16x8 h;
            h[0] = (f16_t)x0; h[1] = (f16_t)x1; h[2] = (f16_t)x2; h[3] = (f16_t)x3;
            h[4] = (f16_t)x4; h[5] = (f16_t)x5; h[6] = (f16_t)x6; h[7] = (f16_t)x7;
            oct[i] = h;
        }
        *reinterpret_cast<f16x8*>(&ERF[(sq4 * 4 + et_) * 512 + lane * 8]) = oct[0];
        if (slot == 0) {
            cidx[edge] = c0;
            unsafeAtomicAdd(&cnts[c0], 1.0f);
        }
    }
    s  += __shfl_xor(s, 16);  s  += __shfl_xor(s, 32);
    sq += __shfl_xor(sq, 16); sq += __shfl_xor(sq, 32);
    if (g4i == 0)
        *reinterpret_cast<float2*>(&SB[edge * 8 + sq4 * 2]) = make_float2(s, sq);
    __syncthreads();

    // ---- phase 1: totals -> LN (2-fma form) -> write X frags
    {
        float4 p0 = *reinterpret_cast<const float4*>(&SB[edge * 8]);
        float4 p1 = *reinterpret_cast<const float4*>(&SB[edge * 8 + 4]);
        float S = p0.x + p0.z + p1.x + p1.z;
        float Q = p0.y + p0.w + p1.y + p1.w;
        const float mean = S * (1.f / 384.f);
        const float rstd = 1.f / sqrtf(Q * (1.f / 384.f) - mean * mean + 1e-5f);
        const float4* g4p = (const float4*)pp;            // elng (pre-rounded)
        const float4* bpp = (const float4*)(pp + 384);    // elnb
        #pragma unroll
        for (int i = 0; i < 3; ++i) {
            int q = (i * 16 + slot) * 2;
            float4 g0 = g4p[q], g1 = g4p[q + 1];
            float4 bb0 = bpp[q], bb1 = bpp[q + 1];
            f16x8 h = oct[i];
            f16x8 y;
            float tt, cc;
            tt = rstd * g0.x; cc = bb0.x - mean * tt; y[0] = (f16_t)((float)h[0] * tt + cc);
            tt = rstd * g0.y; cc = bb0.y - mean * tt; y[1] = (f16_t)((float)h[1] * tt + cc);
            tt = rstd * g0.z; cc = bb0.z - mean * tt; y[2] = (f16_t)((float)h[2] * tt + cc);
            tt = rstd * g0.w; cc = bb0.w - mean * tt; y[3] = (f16_t)((float)h[3] * tt + cc);
            tt = rstd * g1.x; cc = bb1.x - mean * tt; y[4] = (f16_t)((float)h[4] * tt + cc);
            tt = rstd * g1.y; cc = bb1.y - mean * tt; y[5] = (f16_t)((float)h[5] * tt + cc);
            tt = rstd * g1.z; cc = bb1.z - mean * tt; y[6] = (f16_t)((float)h[6] * tt + cc);
            tt = rstd * g1.w; cc = bb1.w - mean * tt; y[7] = (f16_t)((float)h[7] * tt + cc);
            int ks = i * 4 + sq4;
            *reinterpret_cast<f16x8*>(&XF[(ks * 4 + et_) * 512 + lane * 8]) = y;
        }
    }
    __syncthreads();

    // ---- layer 1 (swapped, 2-deep weight prefetch): wave owns cols [wv*16,+16)
    {
        f32x4 acc[4] = {};
        const f16_t* bw = pw;                       // ew0 (NT=16)
        f16x8 wA = *reinterpret_cast<const f16x8*>(&bw[((size_t)(wv) * 64 + lane) * 8]);
        f16x8 wB = *reinterpret_cast<const f16x8*>(&bw[((size_t)(16 + wv) * 64 + lane) * 8]);
        #pragma unroll
        for (int ks = 0; ks < 12; ++ks) {
            f16x8 wN = wB;
            if (ks + 2 < 12)
                wN = *reinterpret_cast<const f16x8*>(
                    &bw[((size_t)((ks + 2) * 16 + wv) * 64 + lane) * 8]);
            #pragma unroll
            for (int et = 0; et < 4; ++et) {
                f16x8 xb = *reinterpret_cast<const f16x8*>(
                    &XF[(ks * 4 + et) * 512 + lane * 8]);
                acc[et] = MFMA16(wA, xb, acc[et]);
            }
            wA = wB; wB = wN;
        }
        __syncthreads();   // all X reads done before overwriting frags 0..7
        float4 bs = *reinterpret_cast<const float4*>(&pp[768 + wv * 16 + g4i * 4]); // eb0
        int ks2 = wv >> 1;
        int lane2 = r16 + 16 * ((wv & 1) * 2 + (g4i >> 1));
        int j0 = (g4i & 1) * 4;
        #pragma unroll
        for (int et = 0; et < 4; ++et) {
            f16x4 hv;
            hv[0] = (f16_t)fmaxf(acc[et][0] + bs.x, 0.f);
            hv[1] = (f16_t)fmaxf(acc[et][1] + bs.y, 0.f);
            hv[2] = (f16_t)fmaxf(acc[et][2] + bs.z, 0.f);
            hv[3] = (f16_t)fmaxf(acc[et][3] + bs.w, 0.f);
            *reinterpret_cast<f16x4*>(&XF[(ks2 * 4 + et) * 512 + lane2 * 8 + j0]) = hv;
        }
    }
    __syncthreads();

    // ---- layer 2 (swapped, prefetch): h2 = relu(h1 @ ew1 + b1)
    {
        f32x4 acc[4] = {};
        const f16_t* bw = pw + 98304;               // ew1 (NT=16)
        f16x8 wA = *reinterpret_cast<const f16x8*>(&bw[((size_t)(wv) * 64 + lane) * 8]);
        f16x8 wB = *reinterpret_cast<const f16x8*>(&bw[((size_t)(16 + wv) * 64 + lane) * 8]);
        #pragma unroll
        for (int ks = 0; ks < 8; ++ks) {
            f16x8 wN = wB;
            if (ks + 2 < 8)
                wN = *reinterpret_cast<const f16x8*>(
                    &bw[((size_t)((ks + 2) * 16 + wv) * 64 + lane) * 8]);
            #pragma unroll
            for (int et = 0; et < 4; ++et) {
                f16x8 xb = *reinterpret_cast<const f16x8*>(
                    &XF[(ks * 4 + et) * 512 + lane * 8]);
                acc[et] = MFMA16(wA, xb, acc[et]);
            }
            wA = wB; wB = wN;
        }
        __syncthreads();   // all h1 reads done before overwrite
        float4 bs = *reinterpret_cast<const float4*>(&pp[1024 + wv * 16 + g4i * 4]); // eb1
        int ks2 = wv >> 1;
        int lane2 = r16 + 16 * ((wv & 1) * 2 + (g4i >> 1));
        int j0 = (g4i & 1) * 4;
        #pragma unroll
        for (int et = 0; et < 4; ++et) {
            f16x4 hv;
            hv[0] = (f16_t)fmaxf(acc[et][0] + bs.x, 0.f);
            hv[1] = (f16_t)fmaxf(acc[et][1] + bs.y, 0.f);
            hv[2] = (f16_t)fmaxf(acc[et][2] + bs.z, 0.f);
            hv[3] = (f16_t)fmaxf(acc[et][3] + bs.w, 0.f);
            *reinterpret_cast<f16x4*>(&XF[(ks2 * 4 + et) * 512 + lane2 * 8 + j0]) = hv;
        }
    }
    __syncthreads();

    // ---- layer 3 + residual (UN-swapped, prefetch): cols [cw*16,+16)
    {
        const int cw = wv & 7;
        const int rw = wv >> 3;
        f32x4 accF[2] = {}, accR[2] = {};
        const f16_t* bw = pw + 163840;              // ew2 (NT=8)
        f16x8 wA = *reinterpret_cast<const f16x8*>(&bw[((size_t)(cw) * 64 + lane) * 8]);
        f16x8 wB = *reinterpret_cast<const f16x8*>(&bw[((size_t)(8 + cw) * 64 + lane) * 8]);
        #pragma unroll
        for (int ks = 0; ks < 8; ++ks) {
            f16x8 wN = wB;
            if (ks + 2 < 8)
                wN = *reinterpret_cast<const f16x8*>(
                    &bw[((size_t)((ks + 2) * 8 + cw) * 64 + lane) * 8]);
            #pragma unroll
            for (int e2 = 0; e2 < 2; ++e2) {
                f16x8 xa = *reinterpret_cast<const f16x8*>(
                    &XF[(ks * 4 + rw * 2 + e2) * 512 + lane * 8]);
                accF[e2] = MFMA16(xa, wA, accF[e2]);
            }
            wA = wB; wB = wN;
        }
        const f16_t* bwL = pw + 196608;             // eLin (NT=8)
        f16x8 lA = *reinterpret_cast<const f16x8*>(&bwL[((size_t)(cw) * 64 + lane) * 8]);
        f16x8 lB = *reinterpret_cast<const f16x8*>(&bwL[((size_t)(8 + cw) * 64 + lane) * 8]);
        #pragma unroll
        for (int ks = 0; ks < 4; ++ks) {
            f16x8 lN = lB;
            if (ks + 2 < 4)
                lN = *reinterpret_cast<const f16x8*>(
                    &bwL[((size_t)((ks + 2) * 8 + cw) * 64 + lane) * 8]);
            #pragma unroll
            for (int e2 = 0; e2 < 2; ++e2) {
                f16x8 ea = *reinterpret_cast<const f16x8*>(
                    &ERF[(ks * 4 + rw * 2 + e2) * 512 + lane * 8]);
                accR[e2] = MFMA16(ea, lA, accR[e2]);
            }
            lA = lB; lB = lN;
        }
        int c = cw * 16 + r16;
        float bias = pp[1280 + c];                  // eb2
        #pragma unroll
        for (int e2 = 0; e2 < 2; ++e2)
            #pragma unroll
            for (int qi = 0; qi < 4; ++qi) {
                int rr = (rw * 2 + e2) * 16 + g4i * 4 + qi;
                float val = accR[e2][qi] + fmaxf(accF[e2][qi] + bias, 0.f);
                size_t eg2 = ebase + rr;
                out_e[eg2 * 128 + c] = val;
                unsafeAtomicAdd(&aggr[(size_t)cidx[rr] * 128 + c], val);
            }
    }
}

// ---------------------------------------------------------------------------
// Node kernel: 32 nodes/block, 512 threads (8 waves). R10 structure,
// pre-rounded params (no bfr on g/b/bias).
// ---------------------------------------------------------------------------
__launch_bounds__(512, 6)
__global__ void node_kernel(
    const float* __restrict__ vfeat, const float* __restrict__ aggr,
    const float* __restrict__ cnts,
    const float* __restrict__ pp,                   // params (node @1408..2559)
    const f16_t* __restrict__ pw,                   // node weight base (nw0)
    float* __restrict__ out_v, int Nn)
{
    __shared__ f16_t X[32 * 264];
    __shared__ f16_t H1[32 * 264];

    const int t    = threadIdx.x;
    const int lane = t & 63;
    const int wv   = t >> 6;           // 0..7
    const size_t nbase = (size_t)blockIdx.x * 32;

    const int nl = t >> 4;
    const int pp16 = t & 15;
    const size_t ng = nbase + nl;
    const bool valid = ng < (size_t)Nn;

    float4 d[4];
    float s = 0.f, sq = 0.f;
    {
        float cmax = 1.f;
        if (valid) cmax = fmaxf(cnts[ng], 1.f);
        const float4* a4 = (const float4*)aggr;
        const float4* v4 = (const float4*)vfeat;
        #pragma unroll
        for (int i = 0; i < 4; ++i) {
            int q = i * 16 + pp16;
            float4 r = make_float4(0.f, 0.f, 0.f, 0.f);
            if (valid) {
                if (q < 32) {
                    r = a4[ng * 32 + q];
                    r.x = r.x / cmax; r.y = r.y / cmax;
                    r.z = r.z / cmax; r.w = r.w / cmax;
                } else {
                    float4 rv = v4[ng * 32 + (q - 32)];
                    r.x = bfr(rv.x); r.y = bfr(rv.y); r.z = bfr(rv.z); r.w = bfr(rv.w);
                }
            }
            d[i] = r;
            s  += r.x + r.y + r.z + r.w;
            sq += r.x*r.x + r.y*r.y + r.z*r.z + r.w*r.w;
        }
    }
    #pragma unroll
    for (int off = 1; off < 16; off <<= 1) {
        s  += __shfl_xor(s, off);
        sq += __shfl_xor(sq, off);
    }
    const float mean = s * (1.f / 256.f);
    const float rstd = 1.f / sqrtf(sq * (1.f / 256.f) - mean * mean + 1e-5f);
    {
        const float4* g4p = (const float4*)(pp + 1408);   // nlng
        const float4* bpp = (const float4*)(pp + 1664);   // nlnb
        #pragma unroll
        for (int i = 0; i < 4; ++i) {
            int q = i * 16 + pp16;
            float4 g = g4p[q]; float4 bb = bpp[q];
            f16x4 y;
            float tt;
            tt = rstd * g.x; y[0] = (f16_t)(d[i].x * tt + (bb.x - mean * tt));
            tt = rstd * g.y; y[1] = (f16_t)(d[i].y * tt + (bb.y - mean * tt));
            tt = rstd * g.z; y[2] = (f16_t)(d[i].z * tt + (bb.z - mean * tt));
            tt = rstd * g.w; y[3] = (f16_t)(d[i].w * tt + (bb.w - mean * tt));
            *reinterpret_cast<f16x4*>(&X[nl * 264 + q * 4]) = y;
        }
    }
    __syncthreads();

    const int r16 = lane & 15;
    const int g4i = lane >> 4;
    const int cb4 = g4i * 4;

    // ---- layer 1 (swapped): wave owns cols [wv*32,+32)
    {
        f32x4 acc[2][2] = {};
        const f16_t* bw = pw;                       // nw0 (NT=16)
        #pragma unroll
        for (int ks = 0; ks < 8; ++ks) {
            f16x8 wa0 = *reinterpret_cast<const f16x8*>(
                &bw[((size_t)(ks * 16 + wv * 2 + 0) * 64 + lane) * 8]);
            f16x8 wa1 = *reinterpret_cast<const f16x8*>(
                &bw[((size_t)(ks * 16 + wv * 2 + 1) * 64 + lane) * 8]);
            #pragma unroll
            for (int nt = 0; nt < 2; ++nt) {
                f16x8 xb = *reinterpret_cast<const f16x8*>(
                    &X[(nt * 16 + r16) * 264 + ks * 32 + g4i * 8]);
                acc[nt][0] = MFMA16(wa0, xb, acc[nt][0]);
                acc[nt][1] = MFMA16(wa1, xb, acc[nt][1]);
            }
        }
        #pragma unroll
        for (int j = 0; j < 2; ++j) {
            int cb = (wv * 2 + j) * 16 + cb4;
            float4 bs = *reinterpret_cast<const float4*>(&pp[1920 + cb]);  // nb0
            #pragma unroll
            for (int nt = 0; nt < 2; ++nt) {
                f16x4 hv;
                hv[0] = (f16_t)fmaxf(acc[nt][j][0] + bs.x, 0.f);
                hv[1] = (f16_t)fmaxf(acc[nt][j][1] + bs.y, 0.f);
                hv[2] = (f16_t)fmaxf(acc[nt][j][2] + bs.z, 0.f);
                hv[3] = (f16_t)fmaxf(acc[nt][j][3] + bs.w, 0.f);
                *reinterpret_cast<f16x4*>(&H1[(nt * 16 + r16) * 264 + cb]) = hv;
            }
        }
    }
    __syncthreads();

    // ---- layer 2 (swapped): into X region
    {
        f32x4 acc[2][2] = {};
        const f16_t* bw = pw + 65536;               // nw1 (NT=16)
        #pragma unroll
        for (int ks = 0; ks < 8; ++ks) {
            f16x8 wa0 = *reinterpret_cast<const f16x8*>(
                &bw[((size_t)(ks * 16 + wv * 2 + 0) * 64 + lane) * 8]);
            f16x8 wa1 = *reinterpret_cast<const f16x8*>(
                &bw[((size_t)(ks * 16 + wv * 2 + 1) * 64 + lane) * 8]);
            #pragma unroll
            for (int nt = 0; nt < 2; ++nt) {
                f16x8 xb = *reinterpret_cast<const f16x8*>(
                    &H1[(nt * 16 + r16) * 264 + ks * 32 + g4i * 8]);
                acc[nt][0] = MFMA16(wa0, xb, acc[nt][0]);
                acc[nt][1] = MFMA16(wa1, xb, acc[nt][1]);
            }
        }
        __syncthreads();
        #pragma unroll
        for (int j = 0; j < 2; ++j) {
            int cb = (wv * 2 + j) * 16 + cb4;
            float4 bs = *reinterpret_cast<const float4*>(&pp[2176 + cb]);  // nb1
            #pragma unroll
            for (int nt = 0; nt < 2; ++nt) {
                f16x4 hv;
                hv[0] = (f16_t)fmaxf(acc[nt][j][0] + bs.x, 0.f);
                hv[1] = (f16_t)fmaxf(acc[nt][j][1] + bs.y, 0.f);
                hv[2] = (f16_t)fmaxf(acc[nt][j][2] + bs.z, 0.f);
                hv[3] = (f16_t)fmaxf(acc[nt][j][3] + bs.w, 0.f);
                *reinterpret_cast<f16x4*>(&X[(nt * 16 + r16) * 264 + cb]) = hv;
            }
        }
    }
    __syncthreads();

    // ---- layer 3 + residual (UN-swapped): wave owns cols [wv*16,+16)
    {
        f32x4 accF[2] = {}, accR[2] = {};
        const f16_t* bw = pw + 131072;              // nw2 (NT=8)
        #pragma unroll
        for (int ks = 0; ks < 8; ++ks) {
            f16x8 wb = *reinterpret_cast<const f16x8*>(
                &bw[((size_t)(ks * 8 + wv) * 64 + lane) * 8]);
            #pragma unroll
            for (int nt = 0; nt < 2; ++nt) {
                f16x8 xa = *reinterpret_cast<const f16x8*>(
                    &X[(nt * 16 + r16) * 264 + ks * 32 + g4i * 8]);
                accF[nt] = MFMA16(xa, wb, accF[nt]);
            }
        }
        const f16_t* bwL = pw + 163840;             // nLin (NT=8)
        #pragma unroll
        for (int ks = 0; ks < 4; ++ks) {
            f16x8 wb = *reinterpret_cast<const f16x8*>(
                &bwL[((size_t)(ks * 8 + wv) * 64 + lane) * 8]);
            #pragma unroll
            for (int nt = 0; nt < 2; ++nt) {
                size_t rv = nbase + (size_t)(nt * 16 + r16);
                if (rv >= (size_t)Nn) rv = (size_t)Nn - 1;
                const float4* src = (const float4*)&vfeat[rv * 128 + ks * 32 + g4i * 8];
                float4 f0 = src[0];
                float4 f1 = src[1];
                f16x8 va;
                va[0] = (f16_t)bfr(f0.x); va[1] = (f16_t)bfr(f0.y);
                va[2] = (f16_t)bfr(f0.z); va[3] = (f16_t)bfr(f0.w);
                va[4] = (f16_t)bfr(f1.x); va[5] = (f16_t)bfr(f1.y);
                va[6] = (f16_t)bfr(f1.z); va[7] = (f16_t)bfr(f1.w);
                accR[nt] = MFMA16(va, wb, accR[nt]);
            }
        }
        int c = wv * 16 + r16;
        float bias = pp[2432 + c];                  // nb2
        #pragma unroll
        for (int nt = 0; nt < 2; ++nt)
            #pragma unroll
            for (int qi = 0; qi < 4; ++qi) {
                int rr = nt * 16 + cb4 + qi;
                size_t ng2 = nbase + rr;
                if (ng2 < (size_t)Nn) {
                    float val = accR[nt][qi] + fmaxf(accF[nt][qi] + bias, 0.f);
                    out_v[ng2 * 128 + c] = val;
                }
            }
    }
}

// ---------------------------------------------------------------------------
extern "C" void kernel_launch(void* const* d_in, const int* in_sizes, int n_in,
                              void* d_out, int out_size, void* d_ws, size_t ws_size,
                              hipStream_t stream)
{
    const float* v    = (const float*)d_in[0];
    const float* e    = (const float*)d_in[1];
    const int*   eidx = (const int*)d_in[2];
    const float* elng = (const float*)d_in[3];
    const float* elnb = (const float*)d_in[4];
    const float* ew0  = (const float*)d_in[5];
    const float* eb0  = (const float*)d_in[6];
    const float* ew1  = (const float*)d_in[7];
    const float* eb1  = (const float*)d_in[8];
    const float* ew2  = (const float*)d_in[9];
    const float* eb2  = (const float*)d_in[10];
    const float* eLin = (const float*)d_in[11];
    const float* nlng = (const float*)d_in[12];
    const float* nlnb = (const float*)d_in[13];
    const float* nw0  = (const float*)d_in[14];
    const float* nb0  = (const float*)d_in[15];
    const float* nw1  = (const float*)d_in[16];
    const float* nb1  = (const float*)d_in[17];
    const float* nw2  = (const float*)d_in[18];
    const float* nb2  = (const float*)d_in[19];
    const float* nLin = (const float*)d_in[20];

    const int Nn = in_sizes[0] / 128;
    const int Ee = in_sizes[1] / 128;

    float* out_v = (float*)d_out;
    float* out_e = out_v + (size_t)Nn * 128;

    float* aggr = (float*)d_ws;                       // [Nn][128] f32
    float* cnts = aggr + (size_t)Nn * 128;            // [Nn] f32
    f16_t* packw = (f16_t*)((char*)d_ws + (size_t)Nn * 129 * 4);  // 393216 f16
    float* pp = (float*)((char*)packw + 393216 * 2);  // 2560 f32 params

    hipMemsetAsync(d_ws, 0, (size_t)Nn * 129 * 4, stream);

    pack_weights_kernel<<<192, 256, 0, stream>>>(ew0, ew1, ew2, eLin,
                                                 nw0, nw1, nw2, nLin, packw);
    pack_params_kernel<<<10, 256, 0, stream>>>(elng, elnb, eb0, eb1, eb2,
                                               nlng, nlnb, nb0, nb1, nb2, pp);

    edge_kernel<<<(Ee + 63) / 64, 1024, 0, stream>>>(v, e, eidx, pp, packw,
                                                     out_e, aggr, cnts, Ee);

    node_kernel<<<(Nn + 31) / 32, 512, 0, stream>>>(v, aggr, cnts, pp,
                                                    packw + 212992, out_v, Nn);
}